// Round 1
// baseline (12887.489 us; speedup 1.0000x reference)
//
#include <hip/hip_runtime.h>
#include <hip/hip_bf16.h>

// DecoderIGCN forward, fp32 correctness-first baseline.
// N=512, D=768, RDIM=100, R=8, L=2.
// Workspace requirement: ~541 MB (135,139,328 floats).

static constexpr long NNpix = 512L * 512L; // 262144

// ---------------------------------------------------------------------------
// Generic tiled GEMM: C[b] = A[b] @ B[b] (optionally B^T), 64x64 tile, BK=16,
// 256 threads, 4x4 per thread. A is [M][K] row-major. B is [K][N] (or [N][K]
// when TRANSB). C is [M][N]. Batch strides in elements.
// ---------------------------------------------------------------------------
template <bool TRANSB, bool RELU, bool BIAS>
__global__ __launch_bounds__(256) void gemm64(
    const float* __restrict__ A, long sA,
    const float* __restrict__ B, long sB,
    float* __restrict__ C, long sC,
    const float* __restrict__ bias,
    int M, int N, int K)
{
    const int bz = blockIdx.z;
    A += (long)bz * sA;
    B += (long)bz * sB;
    C += (long)bz * sC;

    __shared__ float As[16][68];
    __shared__ float Bs[16][68];

    const int tid = threadIdx.x;
    const int m0 = blockIdx.y * 64, n0 = blockIdx.x * 64;
    const int ty = tid >> 4, tx = tid & 15;

    float acc[4][4] = {};

    for (int k0 = 0; k0 < K; k0 += 16) {
        { // A tile: As[kk][mm] = A[m0+mm][k0+kk]
            const int kk = tid & 15;
            const int gk = k0 + kk;
#pragma unroll
            for (int i = 0; i < 4; ++i) {
                const int mm = (tid >> 4) + 16 * i;
                const int gm = m0 + mm;
                As[kk][mm] = (gm < M && gk < K) ? A[(long)gm * K + gk] : 0.f;
            }
        }
        if (!TRANSB) { // Bs[kk][nn] = B[k0+kk][n0+nn]
            const int nn = tid & 63;
            const int gn = n0 + nn;
#pragma unroll
            for (int i = 0; i < 4; ++i) {
                const int kk = (tid >> 6) + 4 * i;
                const int gk = k0 + kk;
                Bs[kk][nn] = (gk < K && gn < N) ? B[(long)gk * N + gn] : 0.f;
            }
        } else { // B is [N][K]: Bs[kk][nn] = B[n0+nn][k0+kk]
            const int kk = tid & 15;
            const int gk = k0 + kk;
#pragma unroll
            for (int i = 0; i < 4; ++i) {
                const int nn = (tid >> 4) + 16 * i;
                const int gn = n0 + nn;
                Bs[kk][nn] = (gk < K && gn < N) ? B[(long)gn * K + gk] : 0.f;
            }
        }
        __syncthreads();
#pragma unroll
        for (int kk = 0; kk < 16; ++kk) {
            const float4 av = *reinterpret_cast<const float4*>(&As[kk][ty * 4]);
            const float4 bv = *reinterpret_cast<const float4*>(&Bs[kk][tx * 4]);
            const float a[4] = {av.x, av.y, av.z, av.w};
            const float b[4] = {bv.x, bv.y, bv.z, bv.w};
#pragma unroll
            for (int i = 0; i < 4; ++i)
#pragma unroll
                for (int j = 0; j < 4; ++j)
                    acc[i][j] = fmaf(a[i], b[j], acc[i][j]);
        }
        __syncthreads();
    }

#pragma unroll
    for (int i = 0; i < 4; ++i) {
        const int gm = m0 + ty * 4 + i;
        if (gm >= M) continue;
#pragma unroll
        for (int j = 0; j < 4; ++j) {
            const int gn = n0 + tx * 4 + j;
            if (gn >= N) continue;
            float v = acc[i][j];
            if (BIAS) v += bias[gn];
            if (RELU) v = fmaxf(v, 0.f);
            C[(long)gm * N + gn] = v;
        }
    }
}

// ---------------------------------------------------------------------------
// 3x3 SAME conv as implicit GEMM. in [Cin][512][512], w [Cout][Cin*9] (OIHW
// flattened), out [Cout][512][512]. Tile: 64 co x 64 consecutive pixels (one
// row segment; 512 % 64 == 0 so a tile never crosses a row).
// ---------------------------------------------------------------------------
template <bool RELU>
__global__ __launch_bounds__(256) void conv3x3(
    const float* __restrict__ in,
    const float* __restrict__ w,
    const float* __restrict__ bias,
    float* __restrict__ out,
    int Cin, int Cout)
{
    const int tid = threadIdx.x;
    const int p0 = blockIdx.x * 64;
    const int c0 = blockIdx.y * 64;
    const int y = p0 >> 9;
    const int x0 = p0 & 511;
    const int K = Cin * 9;

    __shared__ float Ws[16][68];
    __shared__ float Bs[16][68];

    const int ty = tid >> 4, tx = tid & 15;
    float acc[4][4] = {};

    for (int k0 = 0; k0 < K; k0 += 16) {
        { // weights: Ws[kk][mm] = w[c0+mm][k0+kk]
            const int kk = tid & 15;
            const int gk = k0 + kk;
#pragma unroll
            for (int i = 0; i < 4; ++i) {
                const int mm = (tid >> 4) + 16 * i;
                const int gm = c0 + mm;
                Ws[kk][mm] = (gm < Cout && gk < K) ? w[(long)gm * K + gk] : 0.f;
            }
        }
        { // patch: Bs[kk][nn] = in[ci][y+ky-1][x0+nn+kx-1] with zero pad
            const int nn = tid & 63;
#pragma unroll
            for (int i = 0; i < 4; ++i) {
                const int kk = (tid >> 6) + 4 * i;
                const int gk = k0 + kk;
                float v = 0.f;
                if (gk < K) {
                    const int ci = gk / 9;
                    const int t9 = gk - ci * 9;
                    const int ky = t9 / 3;
                    const int kx = t9 - ky * 3;
                    const int yy = y + ky - 1;
                    const int xx = x0 + nn + kx - 1;
                    if (yy >= 0 && yy < 512 && (unsigned)xx < 512u)
                        v = in[((long)ci << 18) + ((long)yy << 9) + xx];
                }
                Bs[kk][nn] = v;
            }
        }
        __syncthreads();
#pragma unroll
        for (int kk = 0; kk < 16; ++kk) {
            const float4 av = *reinterpret_cast<const float4*>(&Ws[kk][ty * 4]);
            const float4 bv = *reinterpret_cast<const float4*>(&Bs[kk][tx * 4]);
            const float a[4] = {av.x, av.y, av.z, av.w};
            const float b[4] = {bv.x, bv.y, bv.z, bv.w};
#pragma unroll
            for (int i = 0; i < 4; ++i)
#pragma unroll
                for (int j = 0; j < 4; ++j)
                    acc[i][j] = fmaf(a[i], b[j], acc[i][j]);
        }
        __syncthreads();
    }

#pragma unroll
    for (int i = 0; i < 4; ++i) {
        const int gm = c0 + ty * 4 + i;
        if (gm >= Cout) continue;
        const float bv = bias[gm];
#pragma unroll
        for (int j = 0; j < 4; ++j) {
            const int gp = p0 + tx * 4 + j;
            float v = acc[i][j] + bv;
            if (RELU) v = fmaxf(v, 0.f);
            out[(long)gm * NNpix + gp] = v;
        }
    }
}

// ---------------------------------------------------------------------------
// LayerNorm over the channel axis of a [C][512][512] tensor: out = LN(x+res).
// One thread per pixel; in-place safe for out==x or out==res.
// ---------------------------------------------------------------------------
__global__ __launch_bounds__(256) void ln_chan(
    const float* __restrict__ x, const float* __restrict__ res,
    const float* __restrict__ g, const float* __restrict__ b,
    float* __restrict__ out, int C)
{
    __shared__ float gs[128], bs[128];
    const int tid = threadIdx.x;
    if (tid < C) { gs[tid] = g[tid]; bs[tid] = b[tid]; }
    __syncthreads();

    const long p = (long)blockIdx.x * 256 + tid;
    float s = 0.f, ss = 0.f;
    for (int c = 0; c < C; ++c) {
        const float v = x[(long)c * NNpix + p] + res[(long)c * NNpix + p];
        s += v; ss += v * v;
    }
    const float mean = s / (float)C;
    const float var = ss / (float)C - mean * mean;
    const float inv = rsqrtf(var + 1e-5f);
    for (int c = 0; c < C; ++c) {
        const float v = x[(long)c * NNpix + p] + res[(long)c * NNpix + p];
        out[(long)c * NNpix + p] = (v - mean) * inv * gs[c] + bs[c];
    }
}

// ---------------------------------------------------------------------------
// iap = rel . rel_mlp_w + b -> softmax over 8 relations -> A_hat = A + I,
// plus block-reduced row sums (over j) into rowsum[8][512] via atomics.
// Grid: (2, 512) so each block covers 256 consecutive j for one row i.
// ---------------------------------------------------------------------------
__global__ __launch_bounds__(256) void rel_softmax_laplace(
    const float* __restrict__ rel,   // [100][512][512]
    const float* __restrict__ w,     // [8][100]
    const float* __restrict__ bvec,  // [8]
    float* __restrict__ Ahat,        // [8][512][512]
    float* __restrict__ rowsum)      // [8][512]
{
    __shared__ float ws[800];
    __shared__ float wred[8][4];
    const int tid = threadIdx.x;
    for (int i = tid; i < 800; i += 256) ws[i] = w[i];
    __syncthreads();

    const int i = blockIdx.y;
    const int j = blockIdx.x * 256 + tid;
    const long p = (long)i * 512 + j;

    float acc[8];
#pragma unroll
    for (int r8 = 0; r8 < 8; ++r8) acc[r8] = bvec[r8];
    for (int r = 0; r < 100; ++r) {
        const float x = rel[(long)r * NNpix + p];
#pragma unroll
        for (int r8 = 0; r8 < 8; ++r8) acc[r8] = fmaf(x, ws[r8 * 100 + r], acc[r8]);
    }
    float m = acc[0];
#pragma unroll
    for (int r8 = 1; r8 < 8; ++r8) m = fmaxf(m, acc[r8]);
    float s = 0.f;
#pragma unroll
    for (int r8 = 0; r8 < 8; ++r8) { acc[r8] = expf(acc[r8] - m); s += acc[r8]; }
    const float inv = 1.f / s;
#pragma unroll
    for (int r8 = 0; r8 < 8; ++r8) {
        const float a = acc[r8] * inv + (i == j ? 1.f : 0.f);
        acc[r8] = a;
        Ahat[(long)r8 * NNpix + p] = a;
    }
    // row-sum reduction over this block's 256 j values
    const int lane = tid & 63, wv = tid >> 6;
#pragma unroll
    for (int r8 = 0; r8 < 8; ++r8) {
        float v = acc[r8];
        for (int off = 32; off > 0; off >>= 1) v += __shfl_down(v, off);
        if (lane == 0) wred[r8][wv] = v;
    }
    __syncthreads();
    if (tid < 8) {
        const float v = wred[tid][0] + wred[tid][1] + wred[tid][2] + wred[tid][3];
        atomicAdd(&rowsum[tid * 512 + i], v);
    }
}

__global__ __launch_bounds__(256) void laplace_norm(
    float* __restrict__ A, const float* __restrict__ rowsum)
{
    const int tid = threadIdx.x;
    const int i = blockIdx.y;
    const int j = blockIdx.x * 256 + tid;
    const long p = (long)i * 512 + j;
#pragma unroll
    for (int r8 = 0; r8 < 8; ++r8) {
        const float di = rsqrtf(rowsum[r8 * 512 + i]);
        const float dj = rsqrtf(rowsum[r8 * 512 + j]);
        A[(long)r8 * NNpix + p] *= di * dj;
    }
}

// ---------------------------------------------------------------------------
// Fused GCN: e[m][r*96+o] = relu( (A[r] @ hf[r])[m][o] + (A[r]^T @ hb[r])[m][o]
//                                 + mh_b[r][o] )
// Tile: 64 rows x 96 cols per block, one r per blockIdx.y.
// ---------------------------------------------------------------------------
__global__ __launch_bounds__(256) void gcn_fused(
    const float* __restrict__ A,   // [8][512][512] normalized
    const float* __restrict__ hf,  // [8][512][96]
    const float* __restrict__ hb,  // [8][512][96]
    const float* __restrict__ mhb, // [8][96]
    float* __restrict__ e)         // [512][768]
{
    const int r = blockIdx.y;
    const int m0 = blockIdx.x * 64;
    const float* Ar = A + (long)r * NNpix;
    const float* hfr = hf + (long)r * 512 * 96;
    const float* hbr = hb + (long)r * 512 * 96;

    __shared__ float As[16][68];
    __shared__ float Ats[16][68];
    __shared__ float Hf[16][96];
    __shared__ float Hb[16][96];

    const int tid = threadIdx.x;
    const int ty = tid >> 4, tx = tid & 15;
    float acc[4][6] = {};

    for (int k0 = 0; k0 < 512; k0 += 16) {
        { // As[kk][mm] = A[r][m0+mm][k0+kk]
            const int kk = tid & 15;
#pragma unroll
            for (int i = 0; i < 4; ++i) {
                const int mm = (tid >> 4) + 16 * i;
                As[kk][mm] = Ar[(long)(m0 + mm) * 512 + k0 + kk];
            }
        }
        { // Ats[kk][mm] = A[r][k0+kk][m0+mm]
            const int mm = tid & 63;
#pragma unroll
            for (int i = 0; i < 4; ++i) {
                const int kk = (tid >> 6) + 4 * i;
                Ats[kk][mm] = Ar[(long)(k0 + kk) * 512 + m0 + mm];
            }
        }
        for (int idx = tid; idx < 16 * 96; idx += 256) {
            const int kk = idx / 96, o = idx - kk * 96;
            Hf[kk][o] = hfr[(long)(k0 + kk) * 96 + o];
            Hb[kk][o] = hbr[(long)(k0 + kk) * 96 + o];
        }
        __syncthreads();
#pragma unroll
        for (int kk = 0; kk < 16; ++kk) {
            const float4 a1 = *reinterpret_cast<const float4*>(&As[kk][ty * 4]);
            const float4 a2 = *reinterpret_cast<const float4*>(&Ats[kk][ty * 4]);
            const float af[4] = {a1.x, a1.y, a1.z, a1.w};
            const float ab[4] = {a2.x, a2.y, a2.z, a2.w};
            float bf[6], bb[6];
#pragma unroll
            for (int jj = 0; jj < 6; ++jj) {
                bf[jj] = Hf[kk][tx * 6 + jj];
                bb[jj] = Hb[kk][tx * 6 + jj];
            }
#pragma unroll
            for (int ii = 0; ii < 4; ++ii)
#pragma unroll
                for (int jj = 0; jj < 6; ++jj)
                    acc[ii][jj] = fmaf(af[ii], bf[jj], fmaf(ab[ii], bb[jj], acc[ii][jj]));
        }
        __syncthreads();
    }

#pragma unroll
    for (int ii = 0; ii < 4; ++ii) {
        const int gm = m0 + ty * 4 + ii;
#pragma unroll
        for (int jj = 0; jj < 6; ++jj) {
            const int o = tx * 6 + jj;
            float v = acc[ii][jj] + mhb[r * 96 + o];
            v = fmaxf(v, 0.f);
            e[(long)gm * 768 + r * 96 + o] = v;
        }
    }
}

// ---------------------------------------------------------------------------
// Row LayerNorm over D=768: out[n] = LN(x[n] + res[n]) * g + b. Block per row.
// ---------------------------------------------------------------------------
__global__ __launch_bounds__(256) void ln_row768(
    const float* __restrict__ x, const float* __restrict__ res,
    const float* __restrict__ g, const float* __restrict__ b,
    float* __restrict__ out)
{
    const int n = blockIdx.x;
    const int tid = threadIdx.x;
    float v[3];
    float s = 0.f, ss = 0.f;
#pragma unroll
    for (int i = 0; i < 3; ++i) {
        const int c = tid + 256 * i;
        v[i] = x[(long)n * 768 + c] + res[(long)n * 768 + c];
        s += v[i]; ss += v[i] * v[i];
    }
    const int lane = tid & 63, wv = tid >> 6;
    for (int off = 32; off > 0; off >>= 1) {
        s += __shfl_down(s, off);
        ss += __shfl_down(ss, off);
    }
    __shared__ float rs[4], rss[4];
    if (lane == 0) { rs[wv] = s; rss[wv] = ss; }
    __syncthreads();
    s = rs[0] + rs[1] + rs[2] + rs[3];
    ss = rss[0] + rss[1] + rss[2] + rss[3];
    const float mean = s * (1.f / 768.f);
    const float var = ss * (1.f / 768.f) - mean * mean;
    const float inv = rsqrtf(var + 1e-5f);
#pragma unroll
    for (int i = 0; i < 3; ++i) {
        const int c = tid + 256 * i;
        out[(long)n * 768 + c] = (v[i] - mean) * inv * g[c] + b[c];
    }
}

// Final rels: out[i][j][r8] = sum_r rel[r][i][j] * w[r8][r] + b[r8]
__global__ __launch_bounds__(256) void final_rels(
    const float* __restrict__ rel, const float* __restrict__ w,
    const float* __restrict__ bvec, float* __restrict__ out)
{
    __shared__ float ws[800];
    const int tid = threadIdx.x;
    for (int i = tid; i < 800; i += 256) ws[i] = w[i];
    __syncthreads();
    const long p = (long)blockIdx.x * 256 + tid;
    float acc[8];
#pragma unroll
    for (int r8 = 0; r8 < 8; ++r8) acc[r8] = bvec[r8];
    for (int r = 0; r < 100; ++r) {
        const float x = rel[(long)r * NNpix + p];
#pragma unroll
        for (int r8 = 0; r8 < 8; ++r8) acc[r8] = fmaf(x, ws[r8 * 100 + r], acc[r8]);
    }
#pragma unroll
    for (int r8 = 0; r8 < 8; ++r8) out[p * 8 + r8] = acc[r8];
}

__global__ __launch_bounds__(256) void copy_f32(
    const float* __restrict__ src, float* __restrict__ dst, long n)
{
    const long i = (long)blockIdx.x * 256 + threadIdx.x;
    if (i < n) dst[i] = src[i];
}

__global__ __launch_bounds__(256) void zero_f32(float* __restrict__ p, long n)
{
    const long i = (long)blockIdx.x * 256 + threadIdx.x;
    if (i < n) p[i] = 0.f;
}

// ---------------------------------------------------------------------------
extern "C" void kernel_launch(void* const* d_in, const int* in_sizes, int n_in,
                              void* d_out, int out_size, void* d_ws, size_t ws_size,
                              hipStream_t stream)
{
    (void)in_sizes; (void)n_in; (void)out_size; (void)ws_size;

    const float* ents_in   = (const float*)d_in[0];
    const float* R_local   = (const float*)d_in[1];
    const float* rel_mlp_w = (const float*)d_in[2];
    const float* rel_mlp_b = (const float*)d_in[3];
    const float* conv1_w   = (const float*)d_in[4];
    const float* conv1_b   = (const float*)d_in[5];
    const float* conv2_w   = (const float*)d_in[6];
    const float* conv2_b   = (const float*)d_in[7];
    const float* pffn_g    = (const float*)d_in[8];
    const float* pffn_b    = (const float*)d_in[9];
    const float* rln_g     = (const float*)d_in[10];
    const float* rln_b     = (const float*)d_in[11];
    const float* mh_wf     = (const float*)d_in[12];
    const float* mh_wb     = (const float*)d_in[13];
    const float* mh_b      = (const float*)d_in[14];
    const float* emlp_w    = (const float*)d_in[15];
    const float* emlp_b    = (const float*)d_in[16];
    const float* eln_g     = (const float*)d_in[17];
    const float* eln_b     = (const float*)d_in[18];
    float* out = (float*)d_out;

    // Workspace layout (floats). T and H1 are phase-disjoint -> share a region.
    float* W    = (float*)d_ws;
    float* T    = W;                      // [100][512][768] = 39,321,600
    float* H1   = W;                      // [200][512][512] = 52,428,800 (union)
    float* RELA = W + 52428800L;          // [100][512][512]
    float* RELB = RELA + 26214400L;       // [100][512][512]
    float* H2   = RELB + 26214400L;       // [100][512][512]
    float* ABUF = H2 + 26214400L;         // [8][512][512]
    float* RSUM = ABUF + 2097152L;        // [8][512]
    float* HF   = RSUM + 4096L;           // [8][512][96]
    float* HB   = HF + 393216L;           // [8][512][96]
    float* EBUF = HB + 393216L;           // [512][768]
    float* E2   = EBUF + 393216L;         // [512][768]
    float* ENTS = E2 + 393216L;           // [512][768]

    copy_f32<<<(393216 + 255) / 256, 256, 0, stream>>>(ents_in, ENTS, 393216);

    float* relPrev = nullptr;
    for (int l = 0; l < 2; ++l) {
        float* relCur = (l == 0) ? RELA : RELB;
        const float* Rl = R_local + (long)l * 100 * 768 * 768;

        // t[r] = ents @ R[r]   (100 batched GEMMs, 512x768x768)
        gemm64<false, false, false><<<dim3(12, 8, 100), 256, 0, stream>>>(
            ENTS, 0, Rl, 589824L, T, 393216L, nullptr, 512, 768, 768);
        // rel[r] = relu(t[r] @ ents^T)   (512x512x768)
        gemm64<true, true, false><<<dim3(8, 8, 100), 256, 0, stream>>>(
            T, 393216L, ENTS, 0, relCur, NNpix, nullptr, 512, 512, 768);
        if (l > 0)
            ln_chan<<<1024, 256, 0, stream>>>(relCur, relPrev,
                rln_g + l * 100, rln_b + l * 100, relCur, 100);

        // posFFN: conv1 (100->200, relu) -> conv2 (200->100) -> LN(+res)
        conv3x3<true><<<dim3(4096, 4), 256, 0, stream>>>(
            relCur, conv1_w + (long)l * 180000, conv1_b + l * 200, H1, 100, 200);
        conv3x3<false><<<dim3(4096, 2), 256, 0, stream>>>(
            H1, conv2_w + (long)l * 180000, conv2_b + l * 100, H2, 200, 100);
        ln_chan<<<1024, 256, 0, stream>>>(H2, relCur,
            pffn_g + l * 100, pffn_b + l * 100, relCur, 100);

        // relation logits -> softmax over r -> A_hat (+I) -> Laplace normalize
        zero_f32<<<16, 256, 0, stream>>>(RSUM, 4096);
        rel_softmax_laplace<<<dim3(2, 512), 256, 0, stream>>>(
            relCur, rel_mlp_w, rel_mlp_b, ABUF, RSUM);
        laplace_norm<<<dim3(2, 512), 256, 0, stream>>>(ABUF, RSUM);

        // hf/hb = ents @ mh_w{f,b}[l][r]   (8 batched 512x96x768)
        gemm64<false, false, false><<<dim3(2, 8, 8), 256, 0, stream>>>(
            ENTS, 0, mh_wf + (long)l * 589824, 73728L, HF, 49152L, nullptr, 512, 96, 768);
        gemm64<false, false, false><<<dim3(2, 8, 8), 256, 0, stream>>>(
            ENTS, 0, mh_wb + (long)l * 589824, 73728L, HB, 49152L, nullptr, 512, 96, 768);
        // e = relu(A@hf + A^T@hb + b), written transposed to [512][768]
        gcn_fused<<<dim3(8, 8), 256, 0, stream>>>(ABUF, HF, HB, mh_b + l * 768, EBUF);

        // ent_mlp: e2 = e @ W^T + b ; ents = LN(e2 + residual)
        gemm64<true, false, true><<<dim3(12, 8, 1), 256, 0, stream>>>(
            EBUF, 0, emlp_w + (long)l * 589824, 0, E2, 0, emlp_b + l * 768, 512, 768, 768);
        ln_row768<<<512, 256, 0, stream>>>(E2, ENTS,
            eln_g + l * 768, eln_b + l * 768, ENTS);

        relPrev = relCur;
    }

    // Outputs: ents [512*768], then rels [512][512][8]
    copy_f32<<<(393216 + 255) / 256, 256, 0, stream>>>(ENTS, out, 393216);
    final_rels<<<1024, 256, 0, stream>>>(relPrev, rel_mlp_w, rel_mlp_b, out + 393216);
}

// Round 3
// 3755.058 us; speedup vs baseline: 3.4320x; 3.4320x over previous
//
#include <hip/hip_runtime.h>
#include <hip/hip_bf16.h>

// DecoderIGCN forward. Round 3: same as round 2 (bf16 MFMA ReRescal + convs)
// with the rel_transpose OOB-write race fixed (guard r0+k8 < 112).
// N=512, D=768, RDIM=100, R=8, L=2.

static constexpr long NNpix = 512L * 512L; // 262144

typedef __attribute__((ext_vector_type(8))) short short8v;
typedef __attribute__((ext_vector_type(4))) float f32x4;

__device__ inline float bf2f(short s) {
    unsigned u = ((unsigned)(unsigned short)s) << 16;
    float f; __builtin_memcpy(&f, &u, 4);
    return f;
}
__device__ inline short f2bf(float f) {
    unsigned u; __builtin_memcpy(&u, &f, 4);
    u += 0x7fff + ((u >> 16) & 1);   // RNE
    return (short)(u >> 16);
}
__device__ inline void gload_lds16(const short* g, short* l) {
    __builtin_amdgcn_global_load_lds(
        (const __attribute__((address_space(1))) unsigned int*)g,
        (__attribute__((address_space(3))) unsigned int*)l, 16, 0, 0);
}

// ---------------------------------------------------------------------------
// bf16 MFMA GEMM: D[M][N] = (relu?)(X[M][K] . Y[N][K]^T), all bf16 (shorts).
// 128x128 tile, BK=32, 256 threads (4 waves, 2x2), 16x16x32 MFMA, 4x4 frags
// per wave. LDS linear [128][32] so global_load_lds (lane*16B) lands right.
// M,N,K multiples of 128/128/32. Batched over blockIdx.z.
// ---------------------------------------------------------------------------
template <bool RELU>
__global__ __launch_bounds__(256) void bgemm_xyt(
    const short* __restrict__ X, long sX,
    const short* __restrict__ Y, long sY,
    short* __restrict__ D, long sD,
    int M, int N, int K)
{
    X += (long)blockIdx.z * sX;
    Y += (long)blockIdx.z * sY;
    D += (long)blockIdx.z * sD;

    __shared__ short Xs[128 * 32];
    __shared__ short Ys[128 * 32];

    const int tid = threadIdx.x, wv = tid >> 6, ln = tid & 63;
    const int wr = wv >> 1, wc = wv & 1;
    const int m0 = blockIdx.y * 128, n0 = blockIdx.x * 128;

    f32x4 acc[4][4] = {};

    const int srow = ln >> 2;        // staging: lane -> row-in-16, k8 group
    const int sk8 = ln & 3;
    const int fr = ln & 15, fk = (ln >> 4) * 8;

    for (int k0 = 0; k0 < K; k0 += 32) {
#pragma unroll
        for (int i = wv; i < 8; i += 4) {
            gload_lds16(X + (long)(m0 + i * 16 + srow) * K + k0 + sk8 * 8,
                        Xs + i * 512);
            gload_lds16(Y + (long)(n0 + i * 16 + srow) * K + k0 + sk8 * 8,
                        Ys + i * 512);
        }
        __syncthreads();
        short8v a[4], b[4];
#pragma unroll
        for (int mi = 0; mi < 4; ++mi)
            a[mi] = *(const short8v*)(Xs + (wr * 64 + mi * 16 + fr) * 32 + fk);
#pragma unroll
        for (int ni = 0; ni < 4; ++ni)
            b[ni] = *(const short8v*)(Ys + (wc * 64 + ni * 16 + fr) * 32 + fk);
#pragma unroll
        for (int mi = 0; mi < 4; ++mi)
#pragma unroll
            for (int ni = 0; ni < 4; ++ni)
                acc[mi][ni] = __builtin_amdgcn_mfma_f32_16x16x32_bf16(
                    a[mi], b[ni], acc[mi][ni], 0, 0, 0);
        __syncthreads();
    }

    const int fv = (ln >> 4) * 4;
#pragma unroll
    for (int mi = 0; mi < 4; ++mi)
#pragma unroll
        for (int ni = 0; ni < 4; ++ni)
#pragma unroll
            for (int v = 0; v < 4; ++v) {
                const int row = m0 + wr * 64 + mi * 16 + fv + v;
                const int col = n0 + wc * 64 + ni * 16 + fr;
                float x = acc[mi][ni][v];
                if (RELU) x = fmaxf(x, 0.f);
                D[(long)row * N + col] = f2bf(x);
            }
}

// ---------------------------------------------------------------------------
// 3x3 SAME conv, bf16 MFMA implicit GEMM over pixel-major input.
// img  [262144][CINP] bf16 (pixel-major, padded channels; pads finite)
// wt   [9][COUT][CIN] bf16 (tap-major)
// out  [262144][OUTP] bf16, pixel-major, + bias (+relu)
// Block: 64 cout x 256 px (one half image row). 4 waves 2x2; wave = 32co x
// 128px = 2x8 fragments. K-chunks of 32 channels; 9 taps share one Is slab.
// ---------------------------------------------------------------------------
template <int CIN, int CINP, int COUT, bool RELU>
__global__ __launch_bounds__(256) void conv3x3_mfma(
    const short* __restrict__ img,
    const short* __restrict__ wt,
    const float* __restrict__ bias,
    short* __restrict__ out, int OUTP)
{
    __shared__ short Is[3][258][40];
    __shared__ short Ws[64][40];

    const int tid = threadIdx.x, wv = tid >> 6, ln = tid & 63;
    const int wm = wv >> 1, wn = wv & 1;
    const int px0 = blockIdx.x * 256;
    const int y = px0 >> 9, x0 = px0 & 511;
    const int c0 = blockIdx.y * 64;

    f32x4 acc[2][8] = {};
    constexpr int NCHUNK = (CIN + 31) / 32;

    for (int cc = 0; cc < NCHUNK; ++cc) {
        const int ci0 = cc * 32;
        // stage image slab: 3 rows x 258 x-positions x 32 channels
        for (int idx = tid; idx < 3096; idx += 256) {
            const int pos = idx >> 2, k8 = idx & 3;
            const int ry = pos / 258, xi = pos - ry * 258;
            const int gy = y + ry - 1, gx = x0 + xi - 1;
            short8v val = {0, 0, 0, 0, 0, 0, 0, 0};
            if ((unsigned)gy < 512u && (unsigned)gx < 512u)
                val = *(const short8v*)(img + ((long)gy * 512 + gx) * CINP + ci0 + k8 * 8);
            *(short8v*)(&Is[ry][xi][k8 * 8]) = val;
        }
        for (int tap = 0; tap < 9; ++tap) {
            __syncthreads();  // Is ready (tap 0) / Ws free (tap > 0)
            {   // stage weights for this tap: Ws[64][32]
                const int r = tid >> 2, ko = (tid & 3) * 8;
                const int co = c0 + r;
                short8v w8;
#pragma unroll
                for (int j = 0; j < 8; ++j) {
                    const int ci = ci0 + ko + j;
                    w8[j] = (co < COUT && ci < CIN)
                        ? wt[((long)tap * COUT + co) * CIN + ci] : (short)0;
                }
                *(short8v*)(&Ws[r][ko]) = w8;
            }
            __syncthreads();
            const int ky = tap / 3, kx = tap - ky * 3;
            const int fr = ln & 15, fk = (ln >> 4) * 8;
            short8v a[2], b[8];
#pragma unroll
            for (int mi = 0; mi < 2; ++mi)
                a[mi] = *(const short8v*)(&Ws[wm * 32 + mi * 16 + fr][fk]);
#pragma unroll
            for (int ni = 0; ni < 8; ++ni)
                b[ni] = *(const short8v*)(&Is[ky][kx + wn * 128 + ni * 16 + fr][fk]);
#pragma unroll
            for (int mi = 0; mi < 2; ++mi)
#pragma unroll
                for (int ni = 0; ni < 8; ++ni)
                    acc[mi][ni] = __builtin_amdgcn_mfma_f32_16x16x32_bf16(
                        a[mi], b[ni], acc[mi][ni], 0, 0, 0);
        }
        __syncthreads();  // protect Is before next chunk's restage
    }

    const int fr = ln & 15, fv = (ln >> 4) * 4;
#pragma unroll
    for (int mi = 0; mi < 2; ++mi)
#pragma unroll
        for (int v = 0; v < 4; ++v) {
            const int co = c0 + wm * 32 + mi * 16 + fv + v;
            if (co >= COUT) continue;
            const float bb = bias[co];
#pragma unroll
            for (int ni = 0; ni < 8; ++ni) {
                const int px = px0 + wn * 128 + ni * 16 + fr;
                float x = acc[mi][ni][v] + bb;
                if (RELU) x = fmaxf(x, 0.f);
                out[(long)px * OUTP + co] = f2bf(x);
            }
        }
}

// ---------------------------------------------------------------------------
// Conversions / transposes
// ---------------------------------------------------------------------------
// Rt[r][e][d] = bf16(R[r][d][e]); 64x64 tiles, grid (12,12,100).
__global__ __launch_bounds__(256) void r_transpose(
    const float* __restrict__ R, short* __restrict__ Rt)
{
    __shared__ float Ts[64][65];
    const int tid = threadIdx.x;
    const long base = (long)blockIdx.z * 589824;
    const int d0 = blockIdx.y * 64, e0 = blockIdx.x * 64;
    const int c = tid & 63, rbase = tid >> 6;
#pragma unroll
    for (int j = 0; j < 16; ++j) {
        const int r = rbase + j * 4;
        Ts[r][c] = R[base + (long)(d0 + r) * 768 + e0 + c];
    }
    __syncthreads();
#pragma unroll
    for (int j = 0; j < 16; ++j) {
        const int e = rbase + j * 4;
        Rt[base + (long)(e0 + e) * 768 + d0 + c] = f2bf(Ts[c][e]);
    }
}

// relp[p][112] = relc[r][p] (channel-major -> pixel-major, zero pads).
// FIX (round 3): guard the store so blockIdx.y==3 (r0=96) doesn't write
// channels 112..127, which lands in the NEXT pixel's row (race -> corruption).
__global__ __launch_bounds__(256) void rel_transpose(
    const short* __restrict__ relc, short* __restrict__ relp)
{
    __shared__ short Ts[64][40];
    const int tid = threadIdx.x;
    const long p0 = (long)blockIdx.x * 64;
    const int r0 = blockIdx.y * 32;
    {
        const int ch = tid >> 3, pxo = (tid & 7) * 8;
        short8v v = {0, 0, 0, 0, 0, 0, 0, 0};
        if (r0 + ch < 100)
            v = *(const short8v*)(relc + (long)(r0 + ch) * NNpix + p0 + pxo);
#pragma unroll
        for (int j = 0; j < 8; ++j) Ts[pxo + j][ch] = v[j];
    }
    __syncthreads();
    const int px = tid >> 2, k8 = (tid & 3) * 8;
    if (r0 + k8 < 112) {
        const short8v o = *(const short8v*)(&Ts[px][k8]);
        *(short8v*)(relp + (p0 + px) * 112 + r0 + k8) = o;
    }
}

__global__ __launch_bounds__(256) void conv_w_convert(
    const float* __restrict__ src, short* __restrict__ dst, int COUT, int CIN)
{
    const int idx = blockIdx.x * 256 + threadIdx.x;
    const int total = 9 * COUT * CIN;
    if (idx >= total) return;
    const int tap = idx / (COUT * CIN);
    const int rem = idx - tap * (COUT * CIN);
    const int co = rem / CIN, ci = rem - co * CIN;
    dst[idx] = f2bf(src[((long)co * CIN + ci) * 9 + tap]);
}

__global__ __launch_bounds__(256) void f32_to_bf16k(
    const float* __restrict__ src, short* __restrict__ dst, long n)
{
    const long i = (long)blockIdx.x * 256 + threadIdx.x;
    if (i < n) dst[i] = f2bf(src[i]);
}

// ---------------------------------------------------------------------------
// Pixel-major channel LN: out[p][c] = LN_c(x[p]+res[p])*g+b  (C=100, CP=112)
// ---------------------------------------------------------------------------
__global__ __launch_bounds__(256) void ln_pix(
    const short* __restrict__ x, const short* __restrict__ res,
    const float* __restrict__ g, const float* __restrict__ b,
    short* __restrict__ out)
{
    __shared__ float gs[100], bs[100];
    const int tid = threadIdx.x;
    if (tid < 100) { gs[tid] = g[tid]; bs[tid] = b[tid]; }
    __syncthreads();
    const long p = (long)blockIdx.x * 256 + tid;
    const short* xr = x + p * 112;
    const short* rr = res + p * 112;
    float v[104];
    float s = 0.f, ss = 0.f;
#pragma unroll
    for (int q = 0; q < 13; ++q) {
        const short8v xa = *(const short8v*)(xr + q * 8);
        const short8v ra = *(const short8v*)(rr + q * 8);
#pragma unroll
        for (int j = 0; j < 8; ++j) {
            const int idx = q * 8 + j;
            const float t = bf2f(xa[j]) + bf2f(ra[j]);
            if (idx < 100) { v[idx] = t; s += t; ss += t * t; }
        }
    }
    const float mean = s * 0.01f;
    const float var = ss * 0.01f - mean * mean;
    const float inv = rsqrtf(var + 1e-5f);
    short* orow = out + p * 112;
#pragma unroll
    for (int q = 0; q < 14; ++q) {
        short8v o;
#pragma unroll
        for (int j = 0; j < 8; ++j) {
            const int idx = q * 8 + j;
            o[j] = (idx < 100) ? f2bf((v[idx] - mean) * inv * gs[idx] + bs[idx])
                               : (short)0;
        }
        *(short8v*)(orow + q * 8) = o;
    }
}

// ---------------------------------------------------------------------------
// softmax over 8 relation logits + A_hat + rowsums (pixel-major bf16 input)
// ---------------------------------------------------------------------------
__global__ __launch_bounds__(256) void rel_softmax_laplace(
    const short* __restrict__ relp,  // [262144][112]
    const float* __restrict__ w,     // [8][100]
    const float* __restrict__ bvec,  // [8]
    float* __restrict__ Ahat,        // [8][512][512]
    float* __restrict__ rowsum)      // [8][512]
{
    __shared__ float ws[800];
    __shared__ float wred[8][4];
    const int tid = threadIdx.x;
    for (int i = tid; i < 800; i += 256) ws[i] = w[i];
    __syncthreads();

    const int i = blockIdx.y;
    const int j = blockIdx.x * 256 + tid;
    const long p = (long)i * 512 + j;
    const short* row = relp + p * 112;

    float acc[8];
#pragma unroll
    for (int r8 = 0; r8 < 8; ++r8) acc[r8] = bvec[r8];
#pragma unroll
    for (int q = 0; q < 13; ++q) {
        const short8v v = *(const short8v*)(row + q * 8);
#pragma unroll
        for (int jj = 0; jj < 8; ++jj) {
            const int r = q * 8 + jj;
            if (r < 100) {
                const float x = bf2f(v[jj]);
#pragma unroll
                for (int r8 = 0; r8 < 8; ++r8)
                    acc[r8] = fmaf(x, ws[r8 * 100 + r], acc[r8]);
            }
        }
    }
    float m = acc[0];
#pragma unroll
    for (int r8 = 1; r8 < 8; ++r8) m = fmaxf(m, acc[r8]);
    float s = 0.f;
#pragma unroll
    for (int r8 = 0; r8 < 8; ++r8) { acc[r8] = expf(acc[r8] - m); s += acc[r8]; }
    const float inv = 1.f / s;
#pragma unroll
    for (int r8 = 0; r8 < 8; ++r8) {
        const float a = acc[r8] * inv + (i == j ? 1.f : 0.f);
        acc[r8] = a;
        Ahat[(long)r8 * NNpix + p] = a;
    }
    const int lane = tid & 63, wvv = tid >> 6;
#pragma unroll
    for (int r8 = 0; r8 < 8; ++r8) {
        float v = acc[r8];
        for (int off = 32; off > 0; off >>= 1) v += __shfl_down(v, off);
        if (lane == 0) wred[r8][wvv] = v;
    }
    __syncthreads();
    if (tid < 8) {
        const float v = wred[tid][0] + wred[tid][1] + wred[tid][2] + wred[tid][3];
        atomicAdd(&rowsum[tid * 512 + i], v);
    }
}

__global__ __launch_bounds__(256) void laplace_norm(
    float* __restrict__ A, const float* __restrict__ rowsum)
{
    const int tid = threadIdx.x;
    const int i = blockIdx.y;
    const int j = blockIdx.x * 256 + tid;
    const long p = (long)i * 512 + j;
#pragma unroll
    for (int r8 = 0; r8 < 8; ++r8) {
        const float di = rsqrtf(rowsum[r8 * 512 + i]);
        const float dj = rsqrtf(rowsum[r8 * 512 + j]);
        A[(long)r8 * NNpix + p] *= di * dj;
    }
}

// ---------------------------------------------------------------------------
// fp32 tiled GEMM (small ops): C = A (.) B(^T), 64x64 tile.
// ---------------------------------------------------------------------------
template <bool TRANSB, bool RELU, bool BIAS>
__global__ __launch_bounds__(256) void gemm64(
    const float* __restrict__ A, long sA,
    const float* __restrict__ B, long sB,
    float* __restrict__ C, long sC,
    const float* __restrict__ bias,
    int M, int N, int K)
{
    const int bz = blockIdx.z;
    A += (long)bz * sA; B += (long)bz * sB; C += (long)bz * sC;
    __shared__ float As[16][68];
    __shared__ float Bs[16][68];
    const int tid = threadIdx.x;
    const int m0 = blockIdx.y * 64, n0 = blockIdx.x * 64;
    const int ty = tid >> 4, tx = tid & 15;
    float acc[4][4] = {};
    for (int k0 = 0; k0 < K; k0 += 16) {
        {
            const int kk = tid & 15, gk = k0 + kk;
#pragma unroll
            for (int i = 0; i < 4; ++i) {
                const int mm = (tid >> 4) + 16 * i, gm = m0 + mm;
                As[kk][mm] = (gm < M && gk < K) ? A[(long)gm * K + gk] : 0.f;
            }
        }
        if (!TRANSB) {
            const int nn = tid & 63, gn = n0 + nn;
#pragma unroll
            for (int i = 0; i < 4; ++i) {
                const int kk = (tid >> 6) + 4 * i, gk = k0 + kk;
                Bs[kk][nn] = (gk < K && gn < N) ? B[(long)gk * N + gn] : 0.f;
            }
        } else {
            const int kk = tid & 15, gk = k0 + kk;
#pragma unroll
            for (int i = 0; i < 4; ++i) {
                const int nn = (tid >> 4) + 16 * i, gn = n0 + nn;
                Bs[kk][nn] = (gk < K && gn < N) ? B[(long)gn * K + gk] : 0.f;
            }
        }
        __syncthreads();
#pragma unroll
        for (int kk = 0; kk < 16; ++kk) {
            const float4 av = *reinterpret_cast<const float4*>(&As[kk][ty * 4]);
            const float4 bv = *reinterpret_cast<const float4*>(&Bs[kk][tx * 4]);
            const float a[4] = {av.x, av.y, av.z, av.w};
            const float b[4] = {bv.x, bv.y, bv.z, bv.w};
#pragma unroll
            for (int i = 0; i < 4; ++i)
#pragma unroll
                for (int j = 0; j < 4; ++j)
                    acc[i][j] = fmaf(a[i], b[j], acc[i][j]);
        }
        __syncthreads();
    }
#pragma unroll
    for (int i = 0; i < 4; ++i) {
        const int gm = m0 + ty * 4 + i;
        if (gm >= M) continue;
#pragma unroll
        for (int j = 0; j < 4; ++j) {
            const int gn = n0 + tx * 4 + j;
            if (gn >= N) continue;
            float v = acc[i][j];
            if (BIAS) v += bias[gn];
            if (RELU) v = fmaxf(v, 0.f);
            C[(long)gm * N + gn] = v;
        }
    }
}

// Fused GCN (fp32)
__global__ __launch_bounds__(256) void gcn_fused(
    const float* __restrict__ A, const float* __restrict__ hf,
    const float* __restrict__ hb, const float* __restrict__ mhb,
    float* __restrict__ e)
{
    const int r = blockIdx.y;
    const int m0 = blockIdx.x * 64;
    const float* Ar = A + (long)r * NNpix;
    const float* hfr = hf + (long)r * 512 * 96;
    const float* hbr = hb + (long)r * 512 * 96;
    __shared__ float As[16][68];
    __shared__ float Ats[16][68];
    __shared__ float Hf[16][96];
    __shared__ float Hb[16][96];
    const int tid = threadIdx.x;
    const int ty = tid >> 4, tx = tid & 15;
    float acc[4][6] = {};
    for (int k0 = 0; k0 < 512; k0 += 16) {
        {
            const int kk = tid & 15;
#pragma unroll
            for (int i = 0; i < 4; ++i) {
                const int mm = (tid >> 4) + 16 * i;
                As[kk][mm] = Ar[(long)(m0 + mm) * 512 + k0 + kk];
            }
        }
        {
            const int mm = tid & 63;
#pragma unroll
            for (int i = 0; i < 4; ++i) {
                const int kk = (tid >> 6) + 4 * i;
                Ats[kk][mm] = Ar[(long)(k0 + kk) * 512 + m0 + mm];
            }
        }
        for (int idx = tid; idx < 16 * 96; idx += 256) {
            const int kk = idx / 96, o = idx - kk * 96;
            Hf[kk][o] = hfr[(long)(k0 + kk) * 96 + o];
            Hb[kk][o] = hbr[(long)(k0 + kk) * 96 + o];
        }
        __syncthreads();
#pragma unroll
        for (int kk = 0; kk < 16; ++kk) {
            const float4 a1 = *reinterpret_cast<const float4*>(&As[kk][ty * 4]);
            const float4 a2 = *reinterpret_cast<const float4*>(&Ats[kk][ty * 4]);
            const float af[4] = {a1.x, a1.y, a1.z, a1.w};
            const float ab[4] = {a2.x, a2.y, a2.z, a2.w};
            float bf[6], bb[6];
#pragma unroll
            for (int jj = 0; jj < 6; ++jj) {
                bf[jj] = Hf[kk][tx * 6 + jj];
                bb[jj] = Hb[kk][tx * 6 + jj];
            }
#pragma unroll
            for (int ii = 0; ii < 4; ++ii)
#pragma unroll
                for (int jj = 0; jj < 6; ++jj)
                    acc[ii][jj] = fmaf(af[ii], bf[jj], fmaf(ab[ii], bb[jj], acc[ii][jj]));
        }
        __syncthreads();
    }
#pragma unroll
    for (int ii = 0; ii < 4; ++ii) {
        const int gm = m0 + ty * 4 + ii;
#pragma unroll
        for (int jj = 0; jj < 6; ++jj) {
            const int o = tx * 6 + jj;
            float v = acc[ii][jj] + mhb[r * 96 + o];
            v = fmaxf(v, 0.f);
            e[(long)gm * 768 + r * 96 + o] = v;
        }
    }
}

__global__ __launch_bounds__(256) void ln_row768(
    const float* __restrict__ x, const float* __restrict__ res,
    const float* __restrict__ g, const float* __restrict__ b,
    float* __restrict__ out)
{
    const int n = blockIdx.x;
    const int tid = threadIdx.x;
    float v[3];
    float s = 0.f, ss = 0.f;
#pragma unroll
    for (int i = 0; i < 3; ++i) {
        const int c = tid + 256 * i;
        v[i] = x[(long)n * 768 + c] + res[(long)n * 768 + c];
        s += v[i]; ss += v[i] * v[i];
    }
    const int lane = tid & 63, wv = tid >> 6;
    for (int off = 32; off > 0; off >>= 1) {
        s += __shfl_down(s, off);
        ss += __shfl_down(ss, off);
    }
    __shared__ float rs[4], rss[4];
    if (lane == 0) { rs[wv] = s; rss[wv] = ss; }
    __syncthreads();
    s = rs[0] + rs[1] + rs[2] + rs[3];
    ss = rss[0] + rss[1] + rss[2] + rss[3];
    const float mean = s * (1.f / 768.f);
    const float var = ss * (1.f / 768.f) - mean * mean;
    const float inv = rsqrtf(var + 1e-5f);
#pragma unroll
    for (int i = 0; i < 3; ++i) {
        const int c = tid + 256 * i;
        out[(long)n * 768 + c] = (v[i] - mean) * inv * g[c] + b[c];
    }
}

// rels output: out[p*8+r8] = sum_r relp[p][r]*w[r8][r] + b[r8]  (fp32 out)
__global__ __launch_bounds__(256) void final_rels(
    const short* __restrict__ relp, const float* __restrict__ w,
    const float* __restrict__ bvec, float* __restrict__ out)
{
    __shared__ float ws[800];
    const int tid = threadIdx.x;
    for (int i = tid; i < 800; i += 256) ws[i] = w[i];
    __syncthreads();
    const long p = (long)blockIdx.x * 256 + tid;
    const short* row = relp + p * 112;
    float acc[8];
#pragma unroll
    for (int r8 = 0; r8 < 8; ++r8) acc[r8] = bvec[r8];
#pragma unroll
    for (int q = 0; q < 13; ++q) {
        const short8v v = *(const short8v*)(row + q * 8);
#pragma unroll
        for (int jj = 0; jj < 8; ++jj) {
            const int r = q * 8 + jj;
            if (r < 100) {
                const float x = bf2f(v[jj]);
#pragma unroll
                for (int r8 = 0; r8 < 8; ++r8)
                    acc[r8] = fmaf(x, ws[r8 * 100 + r], acc[r8]);
            }
        }
    }
#pragma unroll
    for (int r8 = 0; r8 < 8; ++r8) out[p * 8 + r8] = acc[r8];
}

__global__ __launch_bounds__(256) void copy_f32(
    const float* __restrict__ src, float* __restrict__ dst, long n)
{
    const long i = (long)blockIdx.x * 256 + threadIdx.x;
    if (i < n) dst[i] = src[i];
}

__global__ __launch_bounds__(256) void zero_f32(float* __restrict__ p, long n)
{
    const long i = (long)blockIdx.x * 256 + threadIdx.x;
    if (i < n) p[i] = 0.f;
}

// ---------------------------------------------------------------------------
extern "C" void kernel_launch(void* const* d_in, const int* in_sizes, int n_in,
                              void* d_out, int out_size, void* d_ws, size_t ws_size,
                              hipStream_t stream)
{
    (void)in_sizes; (void)n_in; (void)out_size; (void)ws_size;

    const float* ents_in   = (const float*)d_in[0];
    const float* R_local   = (const float*)d_in[1];
    const float* rel_mlp_w = (const float*)d_in[2];
    const float* rel_mlp_b = (const float*)d_in[3];
    const float* conv1_w   = (const float*)d_in[4];
    const float* conv1_b   = (const float*)d_in[5];
    const float* conv2_w   = (const float*)d_in[6];
    const float* conv2_b   = (const float*)d_in[7];
    const float* pffn_g    = (const float*)d_in[8];
    const float* pffn_b    = (const float*)d_in[9];
    const float* rln_g     = (const float*)d_in[10];
    const float* rln_b     = (const float*)d_in[11];
    const float* mh_wf     = (const float*)d_in[12];
    const float* mh_wb     = (const float*)d_in[13];
    const float* mh_b      = (const float*)d_in[14];
    const float* emlp_w    = (const float*)d_in[15];
    const float* emlp_b    = (const float*)d_in[16];
    const float* eln_g     = (const float*)d_in[17];
    const float* eln_b     = (const float*)d_in[18];
    float* out = (float*)d_out;

    // ---- workspace layout (byte offsets, 1 KiB aligned) ----
    char* base = (char*)d_ws;
    size_t off = 0;
    auto alloc = [&](size_t bytes) {
        char* p = base + off;
        off += (bytes + 1023) & ~(size_t)1023;
        return p;
    };
    // union region 1: RTL (118.0MB) / H1T (109.1MB + slack)  [phase-disjoint]
    char* U1 = alloc(117964800 + 4096);
    short* RTL = (short*)U1;                 // [100][768][768] bf16
    short* H1T = (short*)U1;                 // [262144][208] bf16
    // union region 2: TB (78.6MB) / O2P (58.7MB + slack)     [phase-disjoint]
    char* U2 = alloc(78643200 + 4096);
    short* TB  = (short*)U2;                 // [100][512][768] bf16
    short* O2P = (short*)U2;                 // [262144][112] bf16
    short* RELC   = (short*)alloc(52428800 + 4096);  // [100][512][512] bf16
    short* RELP_A = (short*)alloc(58720256 + 4096);  // [262144][112] bf16
    short* RELP_B = (short*)alloc(58720256 + 4096);
    short* W1T = (short*)alloc(360000 * 2);          // [9][200][100] bf16
    short* W2T = (short*)alloc(360000 * 2);          // [9][100][200] bf16
    short* EBF = (short*)alloc(786432 * 2);          // [512][768] bf16
    float* ABUF = (float*)alloc(8388608 * 4 / 4 * 4);       // [8][512][512] f32
    float* RSUM = (float*)alloc(4096 * 4);
    float* HF   = (float*)alloc(393216 * 4);
    float* HB   = (float*)alloc(393216 * 4);
    float* EBUF = (float*)alloc(393216 * 4);
    float* E2   = (float*)alloc(393216 * 4);
    float* ENTS = (float*)alloc(393216 * 4);

    copy_f32<<<1536, 256, 0, stream>>>(ents_in, ENTS, 393216);

    for (int l = 0; l < 2; ++l) {
        short* RELP_cur = (l == 0) ? RELP_A : RELP_B;

        // bf16 ents for this layer
        f32_to_bf16k<<<1536, 256, 0, stream>>>(ENTS, EBF, 393216);

        // R[l] -> transposed bf16
        r_transpose<<<dim3(12, 12, 100), 256, 0, stream>>>(
            R_local + (long)l * 58982400, RTL);

        // t[r] = ents @ R[r] :  X=EBF [512][768], Y=RTL[r] [768][768]
        bgemm_xyt<false><<<dim3(6, 4, 100), 256, 0, stream>>>(
            EBF, 0, RTL, 589824L, TB, 393216L, 512, 768, 768);
        // rel[r] = relu(t[r] @ ents^T) : X=TB[r], Y=EBF
        bgemm_xyt<true><<<dim3(4, 4, 100), 256, 0, stream>>>(
            TB, 393216L, EBF, 0, RELC, 262144L, 512, 512, 768);
        // channel-major -> pixel-major
        rel_transpose<<<dim3(4096, 4), 256, 0, stream>>>(RELC, RELP_cur);
        if (l > 0)
            ln_pix<<<1024, 256, 0, stream>>>(RELP_cur, RELP_A,
                rln_g + l * 100, rln_b + l * 100, RELP_cur);

        // posFFN convs (bf16 MFMA)
        conv_w_convert<<<704, 256, 0, stream>>>(
            conv1_w + (long)l * 180000, W1T, 200, 100);
        conv_w_convert<<<704, 256, 0, stream>>>(
            conv2_w + (long)l * 180000, W2T, 100, 200);
        conv3x3_mfma<100, 112, 200, true><<<dim3(1024, 4), 256, 0, stream>>>(
            RELP_cur, W1T, conv1_b + l * 200, H1T, 208);
        conv3x3_mfma<200, 208, 100, false><<<dim3(1024, 2), 256, 0, stream>>>(
            H1T, W2T, conv2_b + l * 100, O2P, 112);
        ln_pix<<<1024, 256, 0, stream>>>(O2P, RELP_cur,
            pffn_g + l * 100, pffn_b + l * 100, RELP_cur);

        // softmax over relations + Laplace
        zero_f32<<<16, 256, 0, stream>>>(RSUM, 4096);
        rel_softmax_laplace<<<dim3(2, 512), 256, 0, stream>>>(
            RELP_cur, rel_mlp_w, rel_mlp_b, ABUF, RSUM);
        laplace_norm<<<dim3(2, 512), 256, 0, stream>>>(ABUF, RSUM);

        // GCN (fp32 path)
        gemm64<false, false, false><<<dim3(2, 8, 8), 256, 0, stream>>>(
            ENTS, 0, mh_wf + (long)l * 589824, 73728L, HF, 49152L, nullptr, 512, 96, 768);
        gemm64<false, false, false><<<dim3(2, 8, 8), 256, 0, stream>>>(
            ENTS, 0, mh_wb + (long)l * 589824, 73728L, HB, 49152L, nullptr, 512, 96, 768);
        gcn_fused<<<dim3(8, 8), 256, 0, stream>>>(ABUF, HF, HB, mh_b + l * 768, EBUF);
        gemm64<true, false, true><<<dim3(12, 8, 1), 256, 0, stream>>>(
            EBUF, 0, emlp_w + (long)l * 589824, 0, E2, 0, emlp_b + l * 768, 512, 768, 768);
        ln_row768<<<512, 256, 0, stream>>>(E2, ENTS,
            eln_g + l * 768, eln_b + l * 768, ENTS);
    }

    copy_f32<<<1536, 256, 0, stream>>>(ENTS, out, 393216);
    final_rels<<<1024, 256, 0, stream>>>(RELP_B, rel_mlp_w, rel_mlp_b, out + 393216);
}

// Round 4
// 3256.323 us; speedup vs baseline: 3.9577x; 1.1532x over previous
//
#include <hip/hip_runtime.h>
#include <hip/hip_bf16.h>

// DecoderIGCN forward. Round 4: conv3x3 restructured — all-9-tap weight
// fragments held in registers (loaded from a zero-padded weight buffer),
// 2 barriers per ci-chunk instead of 18, 144-MFMA runs between barriers.
// N=512, D=768, RDIM=100, R=8, L=2.

static constexpr long NNpix = 512L * 512L; // 262144

typedef __attribute__((ext_vector_type(8))) short short8v;
typedef __attribute__((ext_vector_type(4))) float f32x4;

__device__ inline float bf2f(short s) {
    unsigned u = ((unsigned)(unsigned short)s) << 16;
    float f; __builtin_memcpy(&f, &u, 4);
    return f;
}
__device__ inline short f2bf(float f) {
    unsigned u; __builtin_memcpy(&u, &f, 4);
    u += 0x7fff + ((u >> 16) & 1);   // RNE
    return (short)(u >> 16);
}
__device__ inline void gload_lds16(const short* g, short* l) {
    __builtin_amdgcn_global_load_lds(
        (const __attribute__((address_space(1))) unsigned int*)g,
        (__attribute__((address_space(3))) unsigned int*)l, 16, 0, 0);
}

// ---------------------------------------------------------------------------
// bf16 MFMA GEMM: D[M][N] = (relu?)(X[M][K] . Y[N][K]^T), all bf16 (shorts).
// 128x128 tile, BK=32, 256 threads (4 waves, 2x2), 16x16x32 MFMA.
// ---------------------------------------------------------------------------
template <bool RELU>
__global__ __launch_bounds__(256) void bgemm_xyt(
    const short* __restrict__ X, long sX,
    const short* __restrict__ Y, long sY,
    short* __restrict__ D, long sD,
    int M, int N, int K)
{
    X += (long)blockIdx.z * sX;
    Y += (long)blockIdx.z * sY;
    D += (long)blockIdx.z * sD;

    __shared__ short Xs[128 * 32];
    __shared__ short Ys[128 * 32];

    const int tid = threadIdx.x, wv = tid >> 6, ln = tid & 63;
    const int wr = wv >> 1, wc = wv & 1;
    const int m0 = blockIdx.y * 128, n0 = blockIdx.x * 128;

    f32x4 acc[4][4] = {};

    const int srow = ln >> 2;
    const int sk8 = ln & 3;
    const int fr = ln & 15, fk = (ln >> 4) * 8;

    for (int k0 = 0; k0 < K; k0 += 32) {
#pragma unroll
        for (int i = wv; i < 8; i += 4) {
            gload_lds16(X + (long)(m0 + i * 16 + srow) * K + k0 + sk8 * 8,
                        Xs + i * 512);
            gload_lds16(Y + (long)(n0 + i * 16 + srow) * K + k0 + sk8 * 8,
                        Ys + i * 512);
        }
        __syncthreads();
        short8v a[4], b[4];
#pragma unroll
        for (int mi = 0; mi < 4; ++mi)
            a[mi] = *(const short8v*)(Xs + (wr * 64 + mi * 16 + fr) * 32 + fk);
#pragma unroll
        for (int ni = 0; ni < 4; ++ni)
            b[ni] = *(const short8v*)(Ys + (wc * 64 + ni * 16 + fr) * 32 + fk);
#pragma unroll
        for (int mi = 0; mi < 4; ++mi)
#pragma unroll
            for (int ni = 0; ni < 4; ++ni)
                acc[mi][ni] = __builtin_amdgcn_mfma_f32_16x16x32_bf16(
                    a[mi], b[ni], acc[mi][ni], 0, 0, 0);
        __syncthreads();
    }

    const int fv = (ln >> 4) * 4;
#pragma unroll
    for (int mi = 0; mi < 4; ++mi)
#pragma unroll
        for (int ni = 0; ni < 4; ++ni)
#pragma unroll
            for (int v = 0; v < 4; ++v) {
                const int row = m0 + wr * 64 + mi * 16 + fv + v;
                const int col = n0 + wc * 64 + ni * 16 + fr;
                float x = acc[mi][ni][v];
                if (RELU) x = fmaxf(x, 0.f);
                D[(long)row * N + col] = f2bf(x);
            }
}

// ---------------------------------------------------------------------------
// 3x3 SAME conv, bf16 MFMA implicit GEMM, pixel-major input.
// img [262144][CINP] bf16; wt [9][COUTP][CINW] bf16 ZERO-PADDED; out
// [262144][OUTP] bf16 + bias (+relu).
// Block: 64 cout x 256 px. Per ci-chunk (32 ch): stage 3x258x32 image slab
// in LDS (2 barriers), hold all 9 taps' weight fragments in registers, then
// 9 x 16 = 144 MFMAs uninterrupted.
// ---------------------------------------------------------------------------
template <int CINW, int NCHUNK, int CINP, int COUTP, int COUT, bool RELU>
__global__ __launch_bounds__(256) void conv3x3_mfma(
    const short* __restrict__ img,
    const short* __restrict__ wt,
    const float* __restrict__ bias,
    short* __restrict__ out, int OUTP)
{
    __shared__ short Is[3][258][40];

    const int tid = threadIdx.x, wv = tid >> 6, ln = tid & 63;
    const int wm = wv >> 1, wn = wv & 1;
    const int px0 = blockIdx.x * 256;
    const int y = px0 >> 9, x0 = px0 & 511;
    const int c0 = blockIdx.y * 64;

    const int fr = ln & 15, fk8 = (ln >> 4) * 8;

    f32x4 acc[2][8] = {};

    for (int cc = 0; cc < NCHUNK; ++cc) {
        const int ci0 = cc * 32;
        if (cc) __syncthreads();           // previous chunk's reads done
        // stage image slab: 3 rows x 258 x-positions x 32 channels
        for (int idx = tid; idx < 3096; idx += 256) {
            const int pos = idx >> 2, k8 = idx & 3;
            const int ry = pos / 258, xi = pos - ry * 258;
            const int gy = y + ry - 1, gx = x0 + xi - 1;
            short8v val = {0, 0, 0, 0, 0, 0, 0, 0};
            if ((unsigned)gy < 512u && (unsigned)gx < 512u)
                val = *(const short8v*)(img + ((long)gy * 512 + gx) * CINP + ci0 + k8 * 8);
            *(short8v*)(&Is[ry][xi][k8 * 8]) = val;
        }
        // all-9-tap weight fragments -> registers (padded buffer, unguarded)
        short8v wf[9][2];
#pragma unroll
        for (int tap = 0; tap < 9; ++tap)
#pragma unroll
            for (int mi = 0; mi < 2; ++mi) {
                const int co = c0 + wm * 32 + mi * 16 + fr;
                wf[tap][mi] = *(const short8v*)(
                    wt + ((long)tap * COUTP + co) * CINW + ci0 + fk8);
            }
        __syncthreads();                   // Is ready
#pragma unroll
        for (int tap = 0; tap < 9; ++tap) {
            const int ky = tap / 3, kx = tap - ky * 3;
            short8v b[8];
#pragma unroll
            for (int ni = 0; ni < 8; ++ni)
                b[ni] = *(const short8v*)(&Is[ky][kx + wn * 128 + ni * 16 + fr][fk8]);
#pragma unroll
            for (int mi = 0; mi < 2; ++mi)
#pragma unroll
                for (int ni = 0; ni < 8; ++ni)
                    acc[mi][ni] = __builtin_amdgcn_mfma_f32_16x16x32_bf16(
                        wf[tap][mi], b[ni], acc[mi][ni], 0, 0, 0);
        }
    }

    const int fv = (ln >> 4) * 4;
#pragma unroll
    for (int mi = 0; mi < 2; ++mi)
#pragma unroll
        for (int v = 0; v < 4; ++v) {
            const int co = c0 + wm * 32 + mi * 16 + fv + v;
            if (co >= COUT) continue;
            const float bb = bias[co];
#pragma unroll
            for (int ni = 0; ni < 8; ++ni) {
                const int px = px0 + wn * 128 + ni * 16 + fr;
                float x = acc[mi][ni][v] + bb;
                if (RELU) x = fmaxf(x, 0.f);
                out[(long)px * OUTP + co] = f2bf(x);
            }
        }
}

// ---------------------------------------------------------------------------
// Conversions / transposes
// ---------------------------------------------------------------------------
__global__ __launch_bounds__(256) void r_transpose(
    const float* __restrict__ R, short* __restrict__ Rt)
{
    __shared__ float Ts[64][65];
    const int tid = threadIdx.x;
    const long base = (long)blockIdx.z * 589824;
    const int d0 = blockIdx.y * 64, e0 = blockIdx.x * 64;
    const int c = tid & 63, rbase = tid >> 6;
#pragma unroll
    for (int j = 0; j < 16; ++j) {
        const int r = rbase + j * 4;
        Ts[r][c] = R[base + (long)(d0 + r) * 768 + e0 + c];
    }
    __syncthreads();
#pragma unroll
    for (int j = 0; j < 16; ++j) {
        const int e = rbase + j * 4;
        Rt[base + (long)(e0 + e) * 768 + d0 + c] = f2bf(Ts[c][e]);
    }
}

// relp[p][112] = relc[r][p] (channel-major -> pixel-major, zero pads).
__global__ __launch_bounds__(256) void rel_transpose(
    const short* __restrict__ relc, short* __restrict__ relp)
{
    __shared__ short Ts[64][40];
    const int tid = threadIdx.x;
    const long p0 = (long)blockIdx.x * 64;
    const int r0 = blockIdx.y * 32;
    {
        const int ch = tid >> 3, pxo = (tid & 7) * 8;
        short8v v = {0, 0, 0, 0, 0, 0, 0, 0};
        if (r0 + ch < 100)
            v = *(const short8v*)(relc + (long)(r0 + ch) * NNpix + p0 + pxo);
#pragma unroll
        for (int j = 0; j < 8; ++j) Ts[pxo + j][ch] = v[j];
    }
    __syncthreads();
    const int px = tid >> 2, k8 = (tid & 3) * 8;
    if (r0 + k8 < 112) {
        const short8v o = *(const short8v*)(&Ts[px][k8]);
        *(short8v*)(relp + (p0 + px) * 112 + r0 + k8) = o;
    }
}

// Zero-padded conv weight convert: src OIHW [COUT][CIN][3][3] fp32 ->
// dst [9][COUTP][CINW] bf16 with zeros outside COUT/CIN.
__global__ __launch_bounds__(256) void conv_w_pad(
    const float* __restrict__ src, short* __restrict__ dst,
    int COUT, int CIN, int COUTP, int CINW)
{
    const int idx = blockIdx.x * 256 + threadIdx.x;
    const int total = 9 * COUTP * CINW;
    if (idx >= total) return;
    const int tap = idx / (COUTP * CINW);
    const int rem = idx - tap * (COUTP * CINW);
    const int co = rem / CINW, ci = rem - co * CINW;
    short v = 0;
    if (co < COUT && ci < CIN)
        v = f2bf(src[((long)co * CIN + ci) * 9 + tap]);
    dst[idx] = v;
}

__global__ __launch_bounds__(256) void f32_to_bf16k(
    const float* __restrict__ src, short* __restrict__ dst, long n)
{
    const long i = (long)blockIdx.x * 256 + threadIdx.x;
    if (i < n) dst[i] = f2bf(src[i]);
}

// ---------------------------------------------------------------------------
// Pixel-major channel LN: out[p][c] = LN_c(x[p]+res[p])*g+b  (C=100, CP=112)
// ---------------------------------------------------------------------------
__global__ __launch_bounds__(256) void ln_pix(
    const short* __restrict__ x, const short* __restrict__ res,
    const float* __restrict__ g, const float* __restrict__ b,
    short* __restrict__ out)
{
    __shared__ float gs[100], bs[100];
    const int tid = threadIdx.x;
    if (tid < 100) { gs[tid] = g[tid]; bs[tid] = b[tid]; }
    __syncthreads();
    const long p = (long)blockIdx.x * 256 + tid;
    const short* xr = x + p * 112;
    const short* rr = res + p * 112;
    float v[104];
    float s = 0.f, ss = 0.f;
#pragma unroll
    for (int q = 0; q < 13; ++q) {
        const short8v xa = *(const short8v*)(xr + q * 8);
        const short8v ra = *(const short8v*)(rr + q * 8);
#pragma unroll
        for (int j = 0; j < 8; ++j) {
            const int idx = q * 8 + j;
            const float t = bf2f(xa[j]) + bf2f(ra[j]);
            if (idx < 100) { v[idx] = t; s += t; ss += t * t; }
        }
    }
    const float mean = s * 0.01f;
    const float var = ss * 0.01f - mean * mean;
    const float inv = rsqrtf(var + 1e-5f);
    short* orow = out + p * 112;
#pragma unroll
    for (int q = 0; q < 14; ++q) {
        short8v o;
#pragma unroll
        for (int j = 0; j < 8; ++j) {
            const int idx = q * 8 + j;
            o[j] = (idx < 100) ? f2bf((v[idx] - mean) * inv * gs[idx] + bs[idx])
                               : (short)0;
        }
        *(short8v*)(orow + q * 8) = o;
    }
}

// ---------------------------------------------------------------------------
// softmax over 8 relation logits + A_hat + rowsums (pixel-major bf16 input)
// ---------------------------------------------------------------------------
__global__ __launch_bounds__(256) void rel_softmax_laplace(
    const short* __restrict__ relp,
    const float* __restrict__ w,
    const float* __restrict__ bvec,
    float* __restrict__ Ahat,
    float* __restrict__ rowsum)
{
    __shared__ float ws[800];
    __shared__ float wred[8][4];
    const int tid = threadIdx.x;
    for (int i = tid; i < 800; i += 256) ws[i] = w[i];
    __syncthreads();

    const int i = blockIdx.y;
    const int j = blockIdx.x * 256 + tid;
    const long p = (long)i * 512 + j;
    const short* row = relp + p * 112;

    float acc[8];
#pragma unroll
    for (int r8 = 0; r8 < 8; ++r8) acc[r8] = bvec[r8];
#pragma unroll
    for (int q = 0; q < 13; ++q) {
        const short8v v = *(const short8v*)(row + q * 8);
#pragma unroll
        for (int jj = 0; jj < 8; ++jj) {
            const int r = q * 8 + jj;
            if (r < 100) {
                const float x = bf2f(v[jj]);
#pragma unroll
                for (int r8 = 0; r8 < 8; ++r8)
                    acc[r8] = fmaf(x, ws[r8 * 100 + r], acc[r8]);
            }
        }
    }
    float m = acc[0];
#pragma unroll
    for (int r8 = 1; r8 < 8; ++r8) m = fmaxf(m, acc[r8]);
    float s = 0.f;
#pragma unroll
    for (int r8 = 0; r8 < 8; ++r8) { acc[r8] = expf(acc[r8] - m); s += acc[r8]; }
    const float inv = 1.f / s;
#pragma unroll
    for (int r8 = 0; r8 < 8; ++r8) {
        const float a = acc[r8] * inv + (i == j ? 1.f : 0.f);
        acc[r8] = a;
        Ahat[(long)r8 * NNpix + p] = a;
    }
    const int lane = tid & 63, wvv = tid >> 6;
#pragma unroll
    for (int r8 = 0; r8 < 8; ++r8) {
        float v = acc[r8];
        for (int off = 32; off > 0; off >>= 1) v += __shfl_down(v, off);
        if (lane == 0) wred[r8][wvv] = v;
    }
    __syncthreads();
    if (tid < 8) {
        const float v = wred[tid][0] + wred[tid][1] + wred[tid][2] + wred[tid][3];
        atomicAdd(&rowsum[tid * 512 + i], v);
    }
}

__global__ __launch_bounds__(256) void laplace_norm(
    float* __restrict__ A, const float* __restrict__ rowsum)
{
    const int tid = threadIdx.x;
    const int i = blockIdx.y;
    const int j = blockIdx.x * 256 + tid;
    const long p = (long)i * 512 + j;
#pragma unroll
    for (int r8 = 0; r8 < 8; ++r8) {
        const float di = rsqrtf(rowsum[r8 * 512 + i]);
        const float dj = rsqrtf(rowsum[r8 * 512 + j]);
        A[(long)r8 * NNpix + p] *= di * dj;
    }
}

// ---------------------------------------------------------------------------
// fp32 tiled GEMM (small ops)
// ---------------------------------------------------------------------------
template <bool TRANSB, bool RELU, bool BIAS>
__global__ __launch_bounds__(256) void gemm64(
    const float* __restrict__ A, long sA,
    const float* __restrict__ B, long sB,
    float* __restrict__ C, long sC,
    const float* __restrict__ bias,
    int M, int N, int K)
{
    const int bz = blockIdx.z;
    A += (long)bz * sA; B += (long)bz * sB; C += (long)bz * sC;
    __shared__ float As[16][68];
    __shared__ float Bs[16][68];
    const int tid = threadIdx.x;
    const int m0 = blockIdx.y * 64, n0 = blockIdx.x * 64;
    const int ty = tid >> 4, tx = tid & 15;
    float acc[4][4] = {};
    for (int k0 = 0; k0 < K; k0 += 16) {
        {
            const int kk = tid & 15, gk = k0 + kk;
#pragma unroll
            for (int i = 0; i < 4; ++i) {
                const int mm = (tid >> 4) + 16 * i, gm = m0 + mm;
                As[kk][mm] = (gm < M && gk < K) ? A[(long)gm * K + gk] : 0.f;
            }
        }
        if (!TRANSB) {
            const int nn = tid & 63, gn = n0 + nn;
#pragma unroll
            for (int i = 0; i < 4; ++i) {
                const int kk = (tid >> 6) + 4 * i, gk = k0 + kk;
                Bs[kk][nn] = (gk < K && gn < N) ? B[(long)gk * N + gn] : 0.f;
            }
        } else {
            const int kk = tid & 15, gk = k0 + kk;
#pragma unroll
            for (int i = 0; i < 4; ++i) {
                const int nn = (tid >> 4) + 16 * i, gn = n0 + nn;
                Bs[kk][nn] = (gk < K && gn < N) ? B[(long)gn * K + gk] : 0.f;
            }
        }
        __syncthreads();
#pragma unroll
        for (int kk = 0; kk < 16; ++kk) {
            const float4 av = *reinterpret_cast<const float4*>(&As[kk][ty * 4]);
            const float4 bv = *reinterpret_cast<const float4*>(&Bs[kk][tx * 4]);
            const float a[4] = {av.x, av.y, av.z, av.w};
            const float b[4] = {bv.x, bv.y, bv.z, bv.w};
#pragma unroll
            for (int i = 0; i < 4; ++i)
#pragma unroll
                for (int j = 0; j < 4; ++j)
                    acc[i][j] = fmaf(a[i], b[j], acc[i][j]);
        }
        __syncthreads();
    }
#pragma unroll
    for (int i = 0; i < 4; ++i) {
        const int gm = m0 + ty * 4 + i;
        if (gm >= M) continue;
#pragma unroll
        for (int j = 0; j < 4; ++j) {
            const int gn = n0 + tx * 4 + j;
            if (gn >= N) continue;
            float v = acc[i][j];
            if (BIAS) v += bias[gn];
            if (RELU) v = fmaxf(v, 0.f);
            C[(long)gm * N + gn] = v;
        }
    }
}

// Fused GCN (fp32)
__global__ __launch_bounds__(256) void gcn_fused(
    const float* __restrict__ A, const float* __restrict__ hf,
    const float* __restrict__ hb, const float* __restrict__ mhb,
    float* __restrict__ e)
{
    const int r = blockIdx.y;
    const int m0 = blockIdx.x * 64;
    const float* Ar = A + (long)r * NNpix;
    const float* hfr = hf + (long)r * 512 * 96;
    const float* hbr = hb + (long)r * 512 * 96;
    __shared__ float As[16][68];
    __shared__ float Ats[16][68];
    __shared__ float Hf[16][96];
    __shared__ float Hb[16][96];
    const int tid = threadIdx.x;
    const int ty = tid >> 4, tx = tid & 15;
    float acc[4][6] = {};
    for (int k0 = 0; k0 < 512; k0 += 16) {
        {
            const int kk = tid & 15;
#pragma unroll
            for (int i = 0; i < 4; ++i) {
                const int mm = (tid >> 4) + 16 * i;
                As[kk][mm] = Ar[(long)(m0 + mm) * 512 + k0 + kk];
            }
        }
        {
            const int mm = tid & 63;
#pragma unroll
            for (int i = 0; i < 4; ++i) {
                const int kk = (tid >> 6) + 4 * i;
                Ats[kk][mm] = Ar[(long)(k0 + kk) * 512 + m0 + mm];
            }
        }
        for (int idx = tid; idx < 16 * 96; idx += 256) {
            const int kk = idx / 96, o = idx - kk * 96;
            Hf[kk][o] = hfr[(long)(k0 + kk) * 96 + o];
            Hb[kk][o] = hbr[(long)(k0 + kk) * 96 + o];
        }
        __syncthreads();
#pragma unroll
        for (int kk = 0; kk < 16; ++kk) {
            const float4 a1 = *reinterpret_cast<const float4*>(&As[kk][ty * 4]);
            const float4 a2 = *reinterpret_cast<const float4*>(&Ats[kk][ty * 4]);
            const float af[4] = {a1.x, a1.y, a1.z, a1.w};
            const float ab[4] = {a2.x, a2.y, a2.z, a2.w};
            float bf[6], bb[6];
#pragma unroll
            for (int jj = 0; jj < 6; ++jj) {
                bf[jj] = Hf[kk][tx * 6 + jj];
                bb[jj] = Hb[kk][tx * 6 + jj];
            }
#pragma unroll
            for (int ii = 0; ii < 4; ++ii)
#pragma unroll
                for (int jj = 0; jj < 6; ++jj)
                    acc[ii][jj] = fmaf(af[ii], bf[jj], fmaf(ab[ii], bb[jj], acc[ii][jj]));
        }
        __syncthreads();
    }
#pragma unroll
    for (int ii = 0; ii < 4; ++ii) {
        const int gm = m0 + ty * 4 + ii;
#pragma unroll
        for (int jj = 0; jj < 6; ++jj) {
            const int o = tx * 6 + jj;
            float v = acc[ii][jj] + mhb[r * 96 + o];
            v = fmaxf(v, 0.f);
            e[(long)gm * 768 + r * 96 + o] = v;
        }
    }
}

__global__ __launch_bounds__(256) void ln_row768(
    const float* __restrict__ x, const float* __restrict__ res,
    const float* __restrict__ g, const float* __restrict__ b,
    float* __restrict__ out)
{
    const int n = blockIdx.x;
    const int tid = threadIdx.x;
    float v[3];
    float s = 0.f, ss = 0.f;
#pragma unroll
    for (int i = 0; i < 3; ++i) {
        const int c = tid + 256 * i;
        v[i] = x[(long)n * 768 + c] + res[(long)n * 768 + c];
        s += v[i]; ss += v[i] * v[i];
    }
    const int lane = tid & 63, wv = tid >> 6;
    for (int off = 32; off > 0; off >>= 1) {
        s += __shfl_down(s, off);
        ss += __shfl_down(ss, off);
    }
    __shared__ float rs[4], rss[4];
    if (lane == 0) { rs[wv] = s; rss[wv] = ss; }
    __syncthreads();
    s = rs[0] + rs[1] + rs[2] + rs[3];
    ss = rss[0] + rss[1] + rss[2] + rss[3];
    const float mean = s * (1.f / 768.f);
    const float var = ss * (1.f / 768.f) - mean * mean;
    const float inv = rsqrtf(var + 1e-5f);
#pragma unroll
    for (int i = 0; i < 3; ++i) {
        const int c = tid + 256 * i;
        out[(long)n * 768 + c] = (v[i] - mean) * inv * g[c] + b[c];
    }
}

__global__ __launch_bounds__(256) void final_rels(
    const short* __restrict__ relp, const float* __restrict__ w,
    const float* __restrict__ bvec, float* __restrict__ out)
{
    __shared__ float ws[800];
    const int tid = threadIdx.x;
    for (int i = tid; i < 800; i += 256) ws[i] = w[i];
    __syncthreads();
    const long p = (long)blockIdx.x * 256 + tid;
    const short* row = relp + p * 112;
    float acc[8];
#pragma unroll
    for (int r8 = 0; r8 < 8; ++r8) acc[r8] = bvec[r8];
#pragma unroll
    for (int q = 0; q < 13; ++q) {
        const short8v v = *(const short8v*)(row + q * 8);
#pragma unroll
        for (int jj = 0; jj < 8; ++jj) {
            const int r = q * 8 + jj;
            if (r < 100) {
                const float x = bf2f(v[jj]);
#pragma unroll
                for (int r8 = 0; r8 < 8; ++r8)
                    acc[r8] = fmaf(x, ws[r8 * 100 + r], acc[r8]);
            }
        }
    }
#pragma unroll
    for (int r8 = 0; r8 < 8; ++r8) out[p * 8 + r8] = acc[r8];
}

__global__ __launch_bounds__(256) void copy_f32(
    const float* __restrict__ src, float* __restrict__ dst, long n)
{
    const long i = (long)blockIdx.x * 256 + threadIdx.x;
    if (i < n) dst[i] = src[i];
}

__global__ __launch_bounds__(256) void zero_f32(float* __restrict__ p, long n)
{
    const long i = (long)blockIdx.x * 256 + threadIdx.x;
    if (i < n) p[i] = 0.f;
}

// ---------------------------------------------------------------------------
extern "C" void kernel_launch(void* const* d_in, const int* in_sizes, int n_in,
                              void* d_out, int out_size, void* d_ws, size_t ws_size,
                              hipStream_t stream)
{
    (void)in_sizes; (void)n_in; (void)out_size; (void)ws_size;

    const float* ents_in   = (const float*)d_in[0];
    const float* R_local   = (const float*)d_in[1];
    const float* rel_mlp_w = (const float*)d_in[2];
    const float* rel_mlp_b = (const float*)d_in[3];
    const float* conv1_w   = (const float*)d_in[4];
    const float* conv1_b   = (const float*)d_in[5];
    const float* conv2_w   = (const float*)d_in[6];
    const float* conv2_b   = (const float*)d_in[7];
    const float* pffn_g    = (const float*)d_in[8];
    const float* pffn_b    = (const float*)d_in[9];
    const float* rln_g     = (const float*)d_in[10];
    const float* rln_b     = (const float*)d_in[11];
    const float* mh_wf     = (const float*)d_in[12];
    const float* mh_wb     = (const float*)d_in[13];
    const float* mh_b      = (const float*)d_in[14];
    const float* emlp_w    = (const float*)d_in[15];
    const float* emlp_b    = (const float*)d_in[16];
    const float* eln_g     = (const float*)d_in[17];
    const float* eln_b     = (const float*)d_in[18];
    float* out = (float*)d_out;

    // ---- workspace layout ----
    char* base = (char*)d_ws;
    size_t off = 0;
    auto alloc = [&](size_t bytes) {
        char* p = base + off;
        off += (bytes + 1023) & ~(size_t)1023;
        return p;
    };
    // union region 1: RTL (118.0MB) / H1T (109.1MB + slack)  [phase-disjoint]
    char* U1 = alloc(117964800 + 4096);
    short* RTL = (short*)U1;                 // [100][768][768] bf16
    short* H1T = (short*)U1;                 // [262144][208] bf16
    // union region 2: TB (78.6MB) / O2P (58.7MB + slack)     [phase-disjoint]
    char* U2 = alloc(78643200 + 4096);
    short* TB  = (short*)U2;                 // [100][512][768] bf16
    short* O2P = (short*)U2;                 // [262144][112] bf16
    short* RELC   = (short*)alloc(52428800 + 4096);  // [100][512][512] bf16
    short* RELP_A = (short*)alloc(58720256 + 4096);  // [262144][112] bf16
    short* RELP_B = (short*)alloc(58720256 + 4096);
    short* W1P = (short*)alloc(294912 * 2);          // [9][256][128] bf16 padded
    short* W2P = (short*)alloc(258048 * 2);          // [9][128][224] bf16 padded
    short* EBF = (short*)alloc(786432 * 2);          // [512][768] bf16
    float* ABUF = (float*)alloc(8388608L * 4);       // [8][512][512] f32
    float* RSUM = (float*)alloc(4096 * 4);
    float* HF   = (float*)alloc(393216 * 4);
    float* HB   = (float*)alloc(393216 * 4);
    float* EBUF = (float*)alloc(393216 * 4);
    float* E2   = (float*)alloc(393216 * 4);
    float* ENTS = (float*)alloc(393216 * 4);

    copy_f32<<<1536, 256, 0, stream>>>(ents_in, ENTS, 393216);

    for (int l = 0; l < 2; ++l) {
        short* RELP_cur = (l == 0) ? RELP_A : RELP_B;

        f32_to_bf16k<<<1536, 256, 0, stream>>>(ENTS, EBF, 393216);

        r_transpose<<<dim3(12, 12, 100), 256, 0, stream>>>(
            R_local + (long)l * 58982400, RTL);

        // t[r] = ents @ R[r]
        bgemm_xyt<false><<<dim3(6, 4, 100), 256, 0, stream>>>(
            EBF, 0, RTL, 589824L, TB, 393216L, 512, 768, 768);
        // rel[r] = relu(t[r] @ ents^T)
        bgemm_xyt<true><<<dim3(4, 4, 100), 256, 0, stream>>>(
            TB, 393216L, EBF, 0, RELC, 262144L, 512, 512, 768);
        rel_transpose<<<dim3(4096, 4), 256, 0, stream>>>(RELC, RELP_cur);
        if (l > 0)
            ln_pix<<<1024, 256, 0, stream>>>(RELP_cur, RELP_A,
                rln_g + l * 100, rln_b + l * 100, RELP_cur);

        // posFFN convs (bf16 MFMA, register-held weights)
        conv_w_pad<<<1152, 256, 0, stream>>>(
            conv1_w + (long)l * 180000, W1P, 200, 100, 256, 128);
        conv_w_pad<<<1008, 256, 0, stream>>>(
            conv2_w + (long)l * 180000, W2P, 100, 200, 128, 224);
        conv3x3_mfma<128, 4, 112, 256, 200, true><<<dim3(1024, 4), 256, 0, stream>>>(
            RELP_cur, W1P, conv1_b + l * 200, H1T, 208);
        conv3x3_mfma<224, 7, 208, 128, 100, false><<<dim3(1024, 2), 256, 0, stream>>>(
            H1T, W2P, conv2_b + l * 100, O2P, 112);
        ln_pix<<<1024, 256, 0, stream>>>(O2P, RELP_cur,
            pffn_g + l * 100, pffn_b + l * 100, RELP_cur);

        // softmax over relations + Laplace
        zero_f32<<<16, 256, 0, stream>>>(RSUM, 4096);
        rel_softmax_laplace<<<dim3(2, 512), 256, 0, stream>>>(
            RELP_cur, rel_mlp_w, rel_mlp_b, ABUF, RSUM);
        laplace_norm<<<dim3(2, 512), 256, 0, stream>>>(ABUF, RSUM);

        // GCN (fp32 path)
        gemm64<false, false, false><<<dim3(2, 8, 8), 256, 0, stream>>>(
            ENTS, 0, mh_wf + (long)l * 589824, 73728L, HF, 49152L, nullptr, 512, 96, 768);
        gemm64<false, false, false><<<dim3(2, 8, 8), 256, 0, stream>>>(
            ENTS, 0, mh_wb + (long)l * 589824, 73728L, HB, 49152L, nullptr, 512, 96, 768);
        gcn_fused<<<dim3(8, 8), 256, 0, stream>>>(ABUF, HF, HB, mh_b + l * 768, EBUF);
        gemm64<true, false, true><<<dim3(12, 8, 1), 256, 0, stream>>>(
            EBUF, 0, emlp_w + (long)l * 589824, 0, E2, 0, emlp_b + l * 768, 512, 768, 768);
        ln_row768<<<512, 256, 0, stream>>>(E2, ENTS,
            eln_g + l * 768, eln_b + l * 768, ENTS);
    }

    copy_f32<<<1536, 256, 0, stream>>>(ENTS, out, 393216);
    final_rels<<<1024, 256, 0, stream>>>(RELP_B, rel_mlp_w, rel_mlp_b, out + 393216);
}

// Round 5
// 3014.775 us; speedup vs baseline: 4.2748x; 1.0801x over previous
//
#include <hip/hip_runtime.h>
#include <hip/hip_bf16.h>

// DecoderIGCN forward. Round 5: conv3x3 "all-cout" restructure — one block
// per 128-px tile computes every output channel (no redundant staging),
// double-buffered LDS slab, issue-early/write-late async staging.
// N=512, D=768, RDIM=100, R=8, L=2.

static constexpr long NNpix = 512L * 512L; // 262144

typedef __attribute__((ext_vector_type(8))) short short8v;
typedef __attribute__((ext_vector_type(4))) float f32x4;

__device__ inline float bf2f(short s) {
    unsigned u = ((unsigned)(unsigned short)s) << 16;
    float f; __builtin_memcpy(&f, &u, 4);
    return f;
}
__device__ inline short f2bf(float f) {
    unsigned u; __builtin_memcpy(&u, &f, 4);
    u += 0x7fff + ((u >> 16) & 1);   // RNE
    return (short)(u >> 16);
}
__device__ inline void gload_lds16(const short* g, short* l) {
    __builtin_amdgcn_global_load_lds(
        (const __attribute__((address_space(1))) unsigned int*)g,
        (__attribute__((address_space(3))) unsigned int*)l, 16, 0, 0);
}

// ---------------------------------------------------------------------------
// bf16 MFMA GEMM: D[M][N] = (relu?)(X[M][K] . Y[N][K]^T), all bf16 (shorts).
// 128x128 tile, BK=32, 256 threads (4 waves, 2x2), 16x16x32 MFMA.
// ---------------------------------------------------------------------------
template <bool RELU>
__global__ __launch_bounds__(256) void bgemm_xyt(
    const short* __restrict__ X, long sX,
    const short* __restrict__ Y, long sY,
    short* __restrict__ D, long sD,
    int M, int N, int K)
{
    X += (long)blockIdx.z * sX;
    Y += (long)blockIdx.z * sY;
    D += (long)blockIdx.z * sD;

    __shared__ short Xs[128 * 32];
    __shared__ short Ys[128 * 32];

    const int tid = threadIdx.x, wv = tid >> 6, ln = tid & 63;
    const int wr = wv >> 1, wc = wv & 1;
    const int m0 = blockIdx.y * 128, n0 = blockIdx.x * 128;

    f32x4 acc[4][4] = {};

    const int srow = ln >> 2;
    const int sk8 = ln & 3;
    const int fr = ln & 15, fk = (ln >> 4) * 8;

    for (int k0 = 0; k0 < K; k0 += 32) {
#pragma unroll
        for (int i = wv; i < 8; i += 4) {
            gload_lds16(X + (long)(m0 + i * 16 + srow) * K + k0 + sk8 * 8,
                        Xs + i * 512);
            gload_lds16(Y + (long)(n0 + i * 16 + srow) * K + k0 + sk8 * 8,
                        Ys + i * 512);
        }
        __syncthreads();
        short8v a[4], b[4];
#pragma unroll
        for (int mi = 0; mi < 4; ++mi)
            a[mi] = *(const short8v*)(Xs + (wr * 64 + mi * 16 + fr) * 32 + fk);
#pragma unroll
        for (int ni = 0; ni < 4; ++ni)
            b[ni] = *(const short8v*)(Ys + (wc * 64 + ni * 16 + fr) * 32 + fk);
#pragma unroll
        for (int mi = 0; mi < 4; ++mi)
#pragma unroll
            for (int ni = 0; ni < 4; ++ni)
                acc[mi][ni] = __builtin_amdgcn_mfma_f32_16x16x32_bf16(
                    a[mi], b[ni], acc[mi][ni], 0, 0, 0);
        __syncthreads();
    }

    const int fv = (ln >> 4) * 4;
#pragma unroll
    for (int mi = 0; mi < 4; ++mi)
#pragma unroll
        for (int ni = 0; ni < 4; ++ni)
#pragma unroll
            for (int v = 0; v < 4; ++v) {
                const int row = m0 + wr * 64 + mi * 16 + fv + v;
                const int col = n0 + wc * 64 + ni * 16 + fr;
                float x = acc[mi][ni][v];
                if (RELU) x = fmaxf(x, 0.f);
                D[(long)row * N + col] = f2bf(x);
            }
}

// ---------------------------------------------------------------------------
// 3x3 SAME conv, bf16 MFMA implicit GEMM, pixel-major, ALL couts per block.
// img [262144][CINP] bf16; wt [9][COUTP][CINW] bf16 zero-padded; out
// [262144][OUTP] bf16 + bias (+relu).
// 512 threads = 8 waves = 4 co-waves x 2 px-waves; wave = MI*16 co x 64 px.
// COUTP = MI*64. Per 32-ch chunk: double-buffered LDS slab [3][130][40],
// stage loads for chunk c+1 issued before computing chunk c (T14), one
// barrier per chunk. Weights per tap-row from L2-hot padded buffer.
// ---------------------------------------------------------------------------
template <int MI, int NCHUNK, int CINP, int CINW, int COUT, bool RELU>
__global__ __launch_bounds__(512) void conv3x3_all(
    const short* __restrict__ img,
    const short* __restrict__ wt,
    const float* __restrict__ bias,
    short* __restrict__ out, int OUTP)
{
    constexpr int COUTP = MI * 64;
    constexpr int NLOAD = 3 * 130 * 4;   // 1560 16B vectors per slab

    __shared__ short Is[2][3][130][40];

    const int tid = threadIdx.x, wv = tid >> 6, ln = tid & 63;
    const int wm = wv >> 1, wn = wv & 1;         // 4 co-waves x 2 px-waves
    const int px0 = blockIdx.x * 128;
    const int y = px0 >> 9, x0 = px0 & 511;
    const int fr = ln & 15, fk8 = (ln >> 4) * 8;

    // precompute this thread's 4 staging slots
    int s_ry[4], s_xi[4], s_k8[4];
    bool s_on[4];
#pragma unroll
    for (int it = 0; it < 4; ++it) {
        const int idx = tid + it * 512;
        s_on[it] = (idx < NLOAD);
        const int pos = idx >> 2;
        const int ry = pos / 130;
        s_ry[it] = ry;
        s_xi[it] = pos - ry * 130;
        s_k8[it] = (idx & 3) * 8;
    }

    f32x4 acc[MI][4] = {};

    short8v sv[4];
    // prologue: load + write chunk 0
#pragma unroll
    for (int it = 0; it < 4; ++it) {
        short8v val = {0, 0, 0, 0, 0, 0, 0, 0};
        if (s_on[it]) {
            const int gy = y + s_ry[it] - 1, gx = x0 + s_xi[it] - 1;
            if ((unsigned)gy < 512u && (unsigned)gx < 512u && s_k8[it] < CINP)
                val = *(const short8v*)(img + ((long)gy * 512 + gx) * CINP + s_k8[it]);
        }
        sv[it] = val;
    }
#pragma unroll
    for (int it = 0; it < 4; ++it)
        if (s_on[it])
            *(short8v*)(&Is[0][s_ry[it]][s_xi[it]][s_k8[it]]) = sv[it];
    __syncthreads();

    for (int cc = 0; cc < NCHUNK; ++cc) {
        const int cur = cc & 1;
        const int ci0 = cc * 32;
        // issue next chunk's global loads early (latency hides under MFMA)
        short8v nv[4];
        if (cc + 1 < NCHUNK) {
            const int nci0 = ci0 + 32;
#pragma unroll
            for (int it = 0; it < 4; ++it) {
                short8v val = {0, 0, 0, 0, 0, 0, 0, 0};
                if (s_on[it]) {
                    const int gy = y + s_ry[it] - 1, gx = x0 + s_xi[it] - 1;
                    const int ci = nci0 + s_k8[it];
                    if ((unsigned)gy < 512u && (unsigned)gx < 512u && ci < CINP)
                        val = *(const short8v*)(img + ((long)gy * 512 + gx) * CINP + ci);
                }
                nv[it] = val;
            }
        }
        // compute chunk cc from Is[cur], tap-row at a time
#pragma unroll
        for (int ky = 0; ky < 3; ++ky) {
            short8v wf[3][MI];
#pragma unroll
            for (int kx = 0; kx < 3; ++kx)
#pragma unroll
                for (int mi = 0; mi < MI; ++mi) {
                    const int co = wm * (MI * 16) + mi * 16 + fr;
                    wf[kx][mi] = *(const short8v*)(
                        wt + ((long)(ky * 3 + kx) * COUTP + co) * CINW + ci0 + fk8);
                }
#pragma unroll
            for (int kx = 0; kx < 3; ++kx)
#pragma unroll
                for (int ni = 0; ni < 4; ++ni) {
                    const short8v b = *(const short8v*)(
                        &Is[cur][ky][kx + wn * 64 + ni * 16 + fr][fk8]);
#pragma unroll
                    for (int mi = 0; mi < MI; ++mi)
                        acc[mi][ni] = __builtin_amdgcn_mfma_f32_16x16x32_bf16(
                            wf[kx][mi], b, acc[mi][ni], 0, 0, 0);
                }
        }
        // write-late into the other buffer, then single barrier
        if (cc + 1 < NCHUNK) {
#pragma unroll
            for (int it = 0; it < 4; ++it)
                if (s_on[it])
                    *(short8v*)(&Is[cur ^ 1][s_ry[it]][s_xi[it]][s_k8[it]]) = nv[it];
        }
        __syncthreads();
    }

    const int fv = (ln >> 4) * 4;
#pragma unroll
    for (int mi = 0; mi < MI; ++mi)
#pragma unroll
        for (int v = 0; v < 4; ++v) {
            const int co = wm * (MI * 16) + mi * 16 + fv + v;
            if (co >= COUT) continue;
            const float bb = bias[co];
#pragma unroll
            for (int ni = 0; ni < 4; ++ni) {
                const int px = px0 + wn * 64 + ni * 16 + fr;
                float x = acc[mi][ni][v] + bb;
                if (RELU) x = fmaxf(x, 0.f);
                out[(long)px * OUTP + co] = f2bf(x);
            }
        }
}

// ---------------------------------------------------------------------------
// Conversions / transposes
// ---------------------------------------------------------------------------
__global__ __launch_bounds__(256) void r_transpose(
    const float* __restrict__ R, short* __restrict__ Rt)
{
    __shared__ float Ts[64][65];
    const int tid = threadIdx.x;
    const long base = (long)blockIdx.z * 589824;
    const int d0 = blockIdx.y * 64, e0 = blockIdx.x * 64;
    const int c = tid & 63, rbase = tid >> 6;
#pragma unroll
    for (int j = 0; j < 16; ++j) {
        const int r = rbase + j * 4;
        Ts[r][c] = R[base + (long)(d0 + r) * 768 + e0 + c];
    }
    __syncthreads();
#pragma unroll
    for (int j = 0; j < 16; ++j) {
        const int e = rbase + j * 4;
        Rt[base + (long)(e0 + e) * 768 + d0 + c] = f2bf(Ts[c][e]);
    }
}

__global__ __launch_bounds__(256) void rel_transpose(
    const short* __restrict__ relc, short* __restrict__ relp)
{
    __shared__ short Ts[64][40];
    const int tid = threadIdx.x;
    const long p0 = (long)blockIdx.x * 64;
    const int r0 = blockIdx.y * 32;
    {
        const int ch = tid >> 3, pxo = (tid & 7) * 8;
        short8v v = {0, 0, 0, 0, 0, 0, 0, 0};
        if (r0 + ch < 100)
            v = *(const short8v*)(relc + (long)(r0 + ch) * NNpix + p0 + pxo);
#pragma unroll
        for (int j = 0; j < 8; ++j) Ts[pxo + j][ch] = v[j];
    }
    __syncthreads();
    const int px = tid >> 2, k8 = (tid & 3) * 8;
    if (r0 + k8 < 112) {
        const short8v o = *(const short8v*)(&Ts[px][k8]);
        *(short8v*)(relp + (p0 + px) * 112 + r0 + k8) = o;
    }
}

// Zero-padded conv weight convert: src OIHW [COUT][CIN][3][3] fp32 ->
// dst [9][COUTP][CINW] bf16 with zeros outside COUT/CIN.
__global__ __launch_bounds__(256) void conv_w_pad(
    const float* __restrict__ src, short* __restrict__ dst,
    int COUT, int CIN, int COUTP, int CINW)
{
    const int idx = blockIdx.x * 256 + threadIdx.x;
    const int total = 9 * COUTP * CINW;
    if (idx >= total) return;
    const int tap = idx / (COUTP * CINW);
    const int rem = idx - tap * (COUTP * CINW);
    const int co = rem / CINW, ci = rem - co * CINW;
    short v = 0;
    if (co < COUT && ci < CIN)
        v = f2bf(src[((long)co * CIN + ci) * 9 + tap]);
    dst[idx] = v;
}

__global__ __launch_bounds__(256) void f32_to_bf16k(
    const float* __restrict__ src, short* __restrict__ dst, long n)
{
    const long i = (long)blockIdx.x * 256 + threadIdx.x;
    if (i < n) dst[i] = f2bf(src[i]);
}

// ---------------------------------------------------------------------------
// Pixel-major channel LN: out[p][c] = LN_c(x[p]+res[p])*g+b  (C=100, CP=112)
// ---------------------------------------------------------------------------
__global__ __launch_bounds__(256) void ln_pix(
    const short* __restrict__ x, const short* __restrict__ res,
    const float* __restrict__ g, const float* __restrict__ b,
    short* __restrict__ out)
{
    __shared__ float gs[100], bs[100];
    const int tid = threadIdx.x;
    if (tid < 100) { gs[tid] = g[tid]; bs[tid] = b[tid]; }
    __syncthreads();
    const long p = (long)blockIdx.x * 256 + tid;
    const short* xr = x + p * 112;
    const short* rr = res + p * 112;
    float v[104];
    float s = 0.f, ss = 0.f;
#pragma unroll
    for (int q = 0; q < 13; ++q) {
        const short8v xa = *(const short8v*)(xr + q * 8);
        const short8v ra = *(const short8v*)(rr + q * 8);
#pragma unroll
        for (int j = 0; j < 8; ++j) {
            const int idx = q * 8 + j;
            const float t = bf2f(xa[j]) + bf2f(ra[j]);
            if (idx < 100) { v[idx] = t; s += t; ss += t * t; }
        }
    }
    const float mean = s * 0.01f;
    const float var = ss * 0.01f - mean * mean;
    const float inv = rsqrtf(var + 1e-5f);
    short* orow = out + p * 112;
#pragma unroll
    for (int q = 0; q < 14; ++q) {
        short8v o;
#pragma unroll
        for (int j = 0; j < 8; ++j) {
            const int idx = q * 8 + j;
            o[j] = (idx < 100) ? f2bf((v[idx] - mean) * inv * gs[idx] + bs[idx])
                               : (short)0;
        }
        *(short8v*)(orow + q * 8) = o;
    }
}

// ---------------------------------------------------------------------------
// softmax over 8 relation logits + A_hat + rowsums (pixel-major bf16 input)
// ---------------------------------------------------------------------------
__global__ __launch_bounds__(256) void rel_softmax_laplace(
    const short* __restrict__ relp,
    const float* __restrict__ w,
    const float* __restrict__ bvec,
    float* __restrict__ Ahat,
    float* __restrict__ rowsum)
{
    __shared__ float ws[800];
    __shared__ float wred[8][4];
    const int tid = threadIdx.x;
    for (int i = tid; i < 800; i += 256) ws[i] = w[i];
    __syncthreads();

    const int i = blockIdx.y;
    const int j = blockIdx.x * 256 + tid;
    const long p = (long)i * 512 + j;
    const short* row = relp + p * 112;

    float acc[8];
#pragma unroll
    for (int r8 = 0; r8 < 8; ++r8) acc[r8] = bvec[r8];
#pragma unroll
    for (int q = 0; q < 13; ++q) {
        const short8v v = *(const short8v*)(row + q * 8);
#pragma unroll
        for (int jj = 0; jj < 8; ++jj) {
            const int r = q * 8 + jj;
            if (r < 100) {
                const float x = bf2f(v[jj]);
#pragma unroll
                for (int r8 = 0; r8 < 8; ++r8)
                    acc[r8] = fmaf(x, ws[r8 * 100 + r], acc[r8]);
            }
        }
    }
    float m = acc[0];
#pragma unroll
    for (int r8 = 1; r8 < 8; ++r8) m = fmaxf(m, acc[r8]);
    float s = 0.f;
#pragma unroll
    for (int r8 = 0; r8 < 8; ++r8) { acc[r8] = expf(acc[r8] - m); s += acc[r8]; }
    const float inv = 1.f / s;
#pragma unroll
    for (int r8 = 0; r8 < 8; ++r8) {
        const float a = acc[r8] * inv + (i == j ? 1.f : 0.f);
        acc[r8] = a;
        Ahat[(long)r8 * NNpix + p] = a;
    }
    const int lane = tid & 63, wvv = tid >> 6;
#pragma unroll
    for (int r8 = 0; r8 < 8; ++r8) {
        float v = acc[r8];
        for (int off = 32; off > 0; off >>= 1) v += __shfl_down(v, off);
        if (lane == 0) wred[r8][wvv] = v;
    }
    __syncthreads();
    if (tid < 8) {
        const float v = wred[tid][0] + wred[tid][1] + wred[tid][2] + wred[tid][3];
        atomicAdd(&rowsum[tid * 512 + i], v);
    }
}

__global__ __launch_bounds__(256) void laplace_norm(
    float* __restrict__ A, const float* __restrict__ rowsum)
{
    const int tid = threadIdx.x;
    const int i = blockIdx.y;
    const int j = blockIdx.x * 256 + tid;
    const long p = (long)i * 512 + j;
#pragma unroll
    for (int r8 = 0; r8 < 8; ++r8) {
        const float di = rsqrtf(rowsum[r8 * 512 + i]);
        const float dj = rsqrtf(rowsum[r8 * 512 + j]);
        A[(long)r8 * NNpix + p] *= di * dj;
    }
}

// ---------------------------------------------------------------------------
// fp32 tiled GEMM (small ops)
// ---------------------------------------------------------------------------
template <bool TRANSB, bool RELU, bool BIAS>
__global__ __launch_bounds__(256) void gemm64(
    const float* __restrict__ A, long sA,
    const float* __restrict__ B, long sB,
    float* __restrict__ C, long sC,
    const float* __restrict__ bias,
    int M, int N, int K)
{
    const int bz = blockIdx.z;
    A += (long)bz * sA; B += (long)bz * sB; C += (long)bz * sC;
    __shared__ float As[16][68];
    __shared__ float Bs[16][68];
    const int tid = threadIdx.x;
    const int m0 = blockIdx.y * 64, n0 = blockIdx.x * 64;
    const int ty = tid >> 4, tx = tid & 15;
    float acc[4][4] = {};
    for (int k0 = 0; k0 < K; k0 += 16) {
        {
            const int kk = tid & 15, gk = k0 + kk;
#pragma unroll
            for (int i = 0; i < 4; ++i) {
                const int mm = (tid >> 4) + 16 * i, gm = m0 + mm;
                As[kk][mm] = (gm < M && gk < K) ? A[(long)gm * K + gk] : 0.f;
            }
        }
        if (!TRANSB) {
            const int nn = tid & 63, gn = n0 + nn;
#pragma unroll
            for (int i = 0; i < 4; ++i) {
                const int kk = (tid >> 6) + 4 * i, gk = k0 + kk;
                Bs[kk][nn] = (gk < K && gn < N) ? B[(long)gk * N + gn] : 0.f;
            }
        } else {
            const int kk = tid & 15, gk = k0 + kk;
#pragma unroll
            for (int i = 0; i < 4; ++i) {
                const int nn = (tid >> 4) + 16 * i, gn = n0 + nn;
                Bs[kk][nn] = (gk < K && gn < N) ? B[(long)gn * K + gk] : 0.f;
            }
        }
        __syncthreads();
#pragma unroll
        for (int kk = 0; kk < 16; ++kk) {
            const float4 av = *reinterpret_cast<const float4*>(&As[kk][ty * 4]);
            const float4 bv = *reinterpret_cast<const float4*>(&Bs[kk][tx * 4]);
            const float a[4] = {av.x, av.y, av.z, av.w};
            const float b[4] = {bv.x, bv.y, bv.z, bv.w};
#pragma unroll
            for (int i = 0; i < 4; ++i)
#pragma unroll
                for (int j = 0; j < 4; ++j)
                    acc[i][j] = fmaf(a[i], b[j], acc[i][j]);
        }
        __syncthreads();
    }
#pragma unroll
    for (int i = 0; i < 4; ++i) {
        const int gm = m0 + ty * 4 + i;
        if (gm >= M) continue;
#pragma unroll
        for (int j = 0; j < 4; ++j) {
            const int gn = n0 + tx * 4 + j;
            if (gn >= N) continue;
            float v = acc[i][j];
            if (BIAS) v += bias[gn];
            if (RELU) v = fmaxf(v, 0.f);
            C[(long)gm * N + gn] = v;
        }
    }
}

// Fused GCN (fp32)
__global__ __launch_bounds__(256) void gcn_fused(
    const float* __restrict__ A, const float* __restrict__ hf,
    const float* __restrict__ hb, const float* __restrict__ mhb,
    float* __restrict__ e)
{
    const int r = blockIdx.y;
    const int m0 = blockIdx.x * 64;
    const float* Ar = A + (long)r * NNpix;
    const float* hfr = hf + (long)r * 512 * 96;
    const float* hbr = hb + (long)r * 512 * 96;
    __shared__ float As[16][68];
    __shared__ float Ats[16][68];
    __shared__ float Hf[16][96];
    __shared__ float Hb[16][96];
    const int tid = threadIdx.x;
    const int ty = tid >> 4, tx = tid & 15;
    float acc[4][6] = {};
    for (int k0 = 0; k0 < 512; k0 += 16) {
        {
            const int kk = tid & 15;
#pragma unroll
            for (int i = 0; i < 4; ++i) {
                const int mm = (tid >> 4) + 16 * i;
                As[kk][mm] = Ar[(long)(m0 + mm) * 512 + k0 + kk];
            }
        }
        {
            const int mm = tid & 63;
#pragma unroll
            for (int i = 0; i < 4; ++i) {
                const int kk = (tid >> 6) + 4 * i;
                Ats[kk][mm] = Ar[(long)(k0 + kk) * 512 + m0 + mm];
            }
        }
        for (int idx = tid; idx < 16 * 96; idx += 256) {
            const int kk = idx / 96, o = idx - kk * 96;
            Hf[kk][o] = hfr[(long)(k0 + kk) * 96 + o];
            Hb[kk][o] = hbr[(long)(k0 + kk) * 96 + o];
        }
        __syncthreads();
#pragma unroll
        for (int kk = 0; kk < 16; ++kk) {
            const float4 a1 = *reinterpret_cast<const float4*>(&As[kk][ty * 4]);
            const float4 a2 = *reinterpret_cast<const float4*>(&Ats[kk][ty * 4]);
            const float af[4] = {a1.x, a1.y, a1.z, a1.w};
            const float ab[4] = {a2.x, a2.y, a2.z, a2.w};
            float bf[6], bb[6];
#pragma unroll
            for (int jj = 0; jj < 6; ++jj) {
                bf[jj] = Hf[kk][tx * 6 + jj];
                bb[jj] = Hb[kk][tx * 6 + jj];
            }
#pragma unroll
            for (int ii = 0; ii < 4; ++ii)
#pragma unroll
                for (int jj = 0; jj < 6; ++jj)
                    acc[ii][jj] = fmaf(af[ii], bf[jj], fmaf(ab[ii], bb[jj], acc[ii][jj]));
        }
        __syncthreads();
    }
#pragma unroll
    for (int ii = 0; ii < 4; ++ii) {
        const int gm = m0 + ty * 4 + ii;
#pragma unroll
        for (int jj = 0; jj < 6; ++jj) {
            const int o = tx * 6 + jj;
            float v = acc[ii][jj] + mhb[r * 96 + o];
            v = fmaxf(v, 0.f);
            e[(long)gm * 768 + r * 96 + o] = v;
        }
    }
}

__global__ __launch_bounds__(256) void ln_row768(
    const float* __restrict__ x, const float* __restrict__ res,
    const float* __restrict__ g, const float* __restrict__ b,
    float* __restrict__ out)
{
    const int n = blockIdx.x;
    const int tid = threadIdx.x;
    float v[3];
    float s = 0.f, ss = 0.f;
#pragma unroll
    for (int i = 0; i < 3; ++i) {
        const int c = tid + 256 * i;
        v[i] = x[(long)n * 768 + c] + res[(long)n * 768 + c];
        s += v[i]; ss += v[i] * v[i];
    }
    const int lane = tid & 63, wv = tid >> 6;
    for (int off = 32; off > 0; off >>= 1) {
        s += __shfl_down(s, off);
        ss += __shfl_down(ss, off);
    }
    __shared__ float rs[4], rss[4];
    if (lane == 0) { rs[wv] = s; rss[wv] = ss; }
    __syncthreads();
    s = rs[0] + rs[1] + rs[2] + rs[3];
    ss = rss[0] + rss[1] + rss[2] + rss[3];
    const float mean = s * (1.f / 768.f);
    const float var = ss * (1.f / 768.f) - mean * mean;
    const float inv = rsqrtf(var + 1e-5f);
#pragma unroll
    for (int i = 0; i < 3; ++i) {
        const int c = tid + 256 * i;
        out[(long)n * 768 + c] = (v[i] - mean) * inv * g[c] + b[c];
    }
}

__global__ __launch_bounds__(256) void final_rels(
    const short* __restrict__ relp, const float* __restrict__ w,
    const float* __restrict__ bvec, float* __restrict__ out)
{
    __shared__ float ws[800];
    const int tid = threadIdx.x;
    for (int i = tid; i < 800; i += 256) ws[i] = w[i];
    __syncthreads();
    const long p = (long)blockIdx.x * 256 + tid;
    const short* row = relp + p * 112;
    float acc[8];
#pragma unroll
    for (int r8 = 0; r8 < 8; ++r8) acc[r8] = bvec[r8];
#pragma unroll
    for (int q = 0; q < 13; ++q) {
        const short8v v = *(const short8v*)(row + q * 8);
#pragma unroll
        for (int jj = 0; jj < 8; ++jj) {
            const int r = q * 8 + jj;
            if (r < 100) {
                const float x = bf2f(v[jj]);
#pragma unroll
                for (int r8 = 0; r8 < 8; ++r8)
                    acc[r8] = fmaf(x, ws[r8 * 100 + r], acc[r8]);
            }
        }
    }
#pragma unroll
    for (int r8 = 0; r8 < 8; ++r8) out[p * 8 + r8] = acc[r8];
}

__global__ __launch_bounds__(256) void copy_f32(
    const float* __restrict__ src, float* __restrict__ dst, long n)
{
    const long i = (long)blockIdx.x * 256 + threadIdx.x;
    if (i < n) dst[i] = src[i];
}

__global__ __launch_bounds__(256) void zero_f32(float* __restrict__ p, long n)
{
    const long i = (long)blockIdx.x * 256 + threadIdx.x;
    if (i < n) p[i] = 0.f;
}

// ---------------------------------------------------------------------------
extern "C" void kernel_launch(void* const* d_in, const int* in_sizes, int n_in,
                              void* d_out, int out_size, void* d_ws, size_t ws_size,
                              hipStream_t stream)
{
    (void)in_sizes; (void)n_in; (void)out_size; (void)ws_size;

    const float* ents_in   = (const float*)d_in[0];
    const float* R_local   = (const float*)d_in[1];
    const float* rel_mlp_w = (const float*)d_in[2];
    const float* rel_mlp_b = (const float*)d_in[3];
    const float* conv1_w   = (const float*)d_in[4];
    const float* conv1_b   = (const float*)d_in[5];
    const float* conv2_w   = (const float*)d_in[6];
    const float* conv2_b   = (const float*)d_in[7];
    const float* pffn_g    = (const float*)d_in[8];
    const float* pffn_b    = (const float*)d_in[9];
    const float* rln_g     = (const float*)d_in[10];
    const float* rln_b     = (const float*)d_in[11];
    const float* mh_wf     = (const float*)d_in[12];
    const float* mh_wb     = (const float*)d_in[13];
    const float* mh_b      = (const float*)d_in[14];
    const float* emlp_w    = (const float*)d_in[15];
    const float* emlp_b    = (const float*)d_in[16];
    const float* eln_g     = (const float*)d_in[17];
    const float* eln_b     = (const float*)d_in[18];
    float* out = (float*)d_out;

    // ---- workspace layout ----
    char* base = (char*)d_ws;
    size_t off = 0;
    auto alloc = [&](size_t bytes) {
        char* p = base + off;
        off += (bytes + 1023) & ~(size_t)1023;
        return p;
    };
    // union region 1: RTL (118.0MB) / H1T (109.1MB + slack)  [phase-disjoint]
    char* U1 = alloc(117964800 + 4096);
    short* RTL = (short*)U1;                 // [100][768][768] bf16
    short* H1T = (short*)U1;                 // [262144][208] bf16
    // union region 2: TB (78.6MB) / O2P (58.7MB + slack)     [phase-disjoint]
    char* U2 = alloc(78643200 + 4096);
    short* TB  = (short*)U2;                 // [100][512][768] bf16
    short* O2P = (short*)U2;                 // [262144][112] bf16
    short* RELC   = (short*)alloc(52428800 + 4096);  // [100][512][512] bf16
    short* RELP_A = (short*)alloc(58720256 + 4096);  // [262144][112] bf16
    short* RELP_B = (short*)alloc(58720256 + 4096);
    short* W1P = (short*)alloc(294912 * 2);          // [9][256][128] bf16 padded
    short* W2P = (short*)alloc(258048 * 2);          // [9][128][224] bf16 padded
    short* EBF = (short*)alloc(786432 * 2);          // [512][768] bf16
    float* ABUF = (float*)alloc(8388608L * 4);       // [8][512][512] f32
    float* RSUM = (float*)alloc(4096 * 4);
    float* HF   = (float*)alloc(393216 * 4);
    float* HB   = (float*)alloc(393216 * 4);
    float* EBUF = (float*)alloc(393216 * 4);
    float* E2   = (float*)alloc(393216 * 4);
    float* ENTS = (float*)alloc(393216 * 4);

    copy_f32<<<1536, 256, 0, stream>>>(ents_in, ENTS, 393216);

    for (int l = 0; l < 2; ++l) {
        short* RELP_cur = (l == 0) ? RELP_A : RELP_B;

        f32_to_bf16k<<<1536, 256, 0, stream>>>(ENTS, EBF, 393216);

        r_transpose<<<dim3(12, 12, 100), 256, 0, stream>>>(
            R_local + (long)l * 58982400, RTL);

        // t[r] = ents @ R[r]
        bgemm_xyt<false><<<dim3(6, 4, 100), 256, 0, stream>>>(
            EBF, 0, RTL, 589824L, TB, 393216L, 512, 768, 768);
        // rel[r] = relu(t[r] @ ents^T)
        bgemm_xyt<true><<<dim3(4, 4, 100), 256, 0, stream>>>(
            TB, 393216L, EBF, 0, RELC, 262144L, 512, 512, 768);
        rel_transpose<<<dim3(4096, 4), 256, 0, stream>>>(RELC, RELP_cur);
        if (l > 0)
            ln_pix<<<1024, 256, 0, stream>>>(RELP_cur, RELP_A,
                rln_g + l * 100, rln_b + l * 100, RELP_cur);

        // posFFN convs (bf16 MFMA, all-cout blocks, double-buffered slab)
        conv_w_pad<<<1152, 256, 0, stream>>>(
            conv1_w + (long)l * 180000, W1P, 200, 100, 256, 128);
        conv_w_pad<<<1008, 256, 0, stream>>>(
            conv2_w + (long)l * 180000, W2P, 100, 200, 128, 224);
        conv3x3_all<4, 4, 112, 128, 200, true><<<2048, 512, 0, stream>>>(
            RELP_cur, W1P, conv1_b + l * 200, H1T, 208);
        conv3x3_all<2, 7, 208, 224, 100, false><<<2048, 512, 0, stream>>>(
            H1T, W2P, conv2_b + l * 100, O2P, 112);
        ln_pix<<<1024, 256, 0, stream>>>(O2P, RELP_cur,
            pffn_g + l * 100, pffn_b + l * 100, RELP_cur);

        // softmax over relations + Laplace
        zero_f32<<<16, 256, 0, stream>>>(RSUM, 4096);
        rel_softmax_laplace<<<dim3(2, 512), 256, 0, stream>>>(
            RELP_cur, rel_mlp_w, rel_mlp_b, ABUF, RSUM);
        laplace_norm<<<dim3(2, 512), 256, 0, stream>>>(ABUF, RSUM);

        // GCN (fp32 path)
        gemm64<false, false, false><<<dim3(2, 8, 8), 256, 0, stream>>>(
            ENTS, 0, mh_wf + (long)l * 589824, 73728L, HF, 49152L, nullptr, 512, 96, 768);
        gemm64<false, false, false><<<dim3(2, 8, 8), 256, 0, stream>>>(
            ENTS, 0, mh_wb + (long)l * 589824, 73728L, HB, 49152L, nullptr, 512, 96, 768);
        gcn_fused<<<dim3(8, 8), 256, 0, stream>>>(ABUF, HF, HB, mh_b + l * 768, EBUF);
        gemm64<true, false, true><<<dim3(12, 8, 1), 256, 0, stream>>>(
            EBUF, 0, emlp_w + (long)l * 589824, 0, E2, 0, emlp_b + l * 768, 512, 768, 768);
        ln_row768<<<512, 256, 0, stream>>>(E2, ENTS,
            eln_g + l * 768, eln_b + l * 768, ENTS);
    }

    copy_f32<<<1536, 256, 0, stream>>>(ENTS, out, 393216);
    final_rels<<<1024, 256, 0, stream>>>(RELP_B, rel_mlp_w, rel_mlp_b, out + 393216);
}